// Round 7
// baseline (362.718 us; speedup 1.0000x reference)
//
#include <hip/hip_runtime.h>
#include <cstdint>
#include <cstddef>

#define DIM 1024
#define HEADS 16
#define HD 64
#define DFF 4096
#define TSEQ 2048
#define EPS 1e-5f

// s_waitcnt immediates: vmcnt bits[3:0]|[15:14], expcnt bits[6:4], lgkmcnt bits[11:8]
#define WAITCNT_VM4 0xF74        // vmcnt=4, lgkm=15 (no wait)
#define WAITCNT_VM0 0xF70        // vmcnt=0, lgkm=15
#define WAITCNT_VM8 0xF78        // vmcnt=8, lgkm=15
#define WAITCNT_LGKM0 0xC07F     // lgkm=0, vmcnt=63 (no wait) -- drain DS, keep DMA in flight

typedef __bf16 bf16x8 __attribute__((ext_vector_type(8)));
typedef __bf16 bf16x4 __attribute__((ext_vector_type(4)));
typedef float floatx4 __attribute__((ext_vector_type(4)));

__device__ __forceinline__ unsigned short f2bf(float f) {
  union { float f; unsigned int u; } v; v.f = f;
  return (unsigned short)((v.u + 0x7FFFu + ((v.u >> 16) & 1u)) >> 16);
}

// raw v_exp_f32: computes 2^x (log2e is pre-folded into the Q scale)
__device__ __forceinline__ float exp2_fast(float x) {
#if __has_builtin(__builtin_amdgcn_exp2f)
  return __builtin_amdgcn_exp2f(x);
#else
  float r;
  asm("v_exp_f32 %0, %1" : "=v"(r) : "v"(x));
  return r;
#endif
}

// tanh-form GELU: max |err| vs exact-erf gelu ~3e-3 (negligible vs bf16 path noise)
__device__ __forceinline__ float gelu_f(float v) {
  const float u = v * (0.7978845608f + 0.0356774081f * v * v);
  const float e = __expf(2.0f * u);
  const float t = 1.0f - 2.0f / (e + 1.0f);
  return 0.5f * v * (1.0f + t);
}

__device__ __forceinline__ void async16(const void* g, void* l) {
  __builtin_amdgcn_global_load_lds(
      (const __attribute__((address_space(1))) void*)g,
      (__attribute__((address_space(3))) void*)l, 16, 0, 0);
}

// ---------------- fused prep: x->bf16 + 4 weight transposes (one launch) ----------------
__global__ __launch_bounds__(256) void prep_all(const float* __restrict__ x,
                                                const float* __restrict__ Wqkv,
                                                const float* __restrict__ Wout,
                                                const float* __restrict__ W1,
                                                const float* __restrict__ W2,
                                                unsigned short* __restrict__ xb,
                                                unsigned short* __restrict__ WqkvT,
                                                unsigned short* __restrict__ WoutT,
                                                unsigned short* __restrict__ W1T,
                                                unsigned short* __restrict__ W2T) {
  const int bid = blockIdx.x;
  const int tid = threadIdx.x;
  if (bid < 4096) {  // x -> bf16, float4 per thread
    const int i = bid * 256 + tid;
    float4 v = ((const float4*)x)[i];
    ushort4 o;
    o.x = f2bf(v.x); o.y = f2bf(v.y); o.z = f2bf(v.z); o.w = f2bf(v.w);
    ((ushort4*)xb)[i] = o;
    return;
  }
  int id = bid - 4096;
  const float* src; unsigned short* dst; int R, C, gx;
  if (id < 3072)      {            src = Wqkv; dst = WqkvT; R = 1024; C = 3072; gx = 96; }
  else if (id < 4096) { id -= 3072; src = Wout; dst = WoutT; R = 1024; C = 1024; gx = 32; }
  else if (id < 8192) { id -= 4096; src = W1;   dst = W1T;   R = 1024; C = 4096; gx = 128; }
  else                { id -= 8192; src = W2;   dst = W2T;   R = 4096; C = 1024; gx = 32; }
  const int c0 = (id % gx) * 32, r0 = (id / gx) * 32;
  const int tx = tid & 31, ty = tid >> 5;  // 32 x 8
  __shared__ float tile[32][33];
#pragma unroll
  for (int i = 0; i < 32; i += 8)
    tile[ty + i][tx] = src[(size_t)(r0 + ty + i) * C + c0 + tx];
  __syncthreads();
#pragma unroll
  for (int i = 0; i < 32; i += 8)
    dst[(size_t)(c0 + ty + i) * R + r0 + tx] = f2bf(tile[tx][ty + i]);
}

// ============ 256x256-tile 8-phase GEMM core (m201-template; harness-proven r6) ============
// 512 threads = 8 waves (2M x 4N); per-wave output 128x64 (acc[8][4]); BK=64/K-step,
// 64 MFMA/wave/K-step in 4 phases x 16 MFMA. LDS 128 KiB: 2 K-step buffers x
// (A 256x64 | B 256x64), swizzled chunk^(row&7) (linear DMA dest + pre-swizzled global
// source + XOR on read). ph0 issues ALL next-K-step staging; each phase {af ds_reads ->
// barrier -> lgkm0 -> setprio -> 16 MFMA -> setprio -> barrier}; vmcnt(0) only at ph3.
// Declares/leaves in scope: lane,wv,l16,quad,wr,wc and acc[8][4] for the epilogue.
#define GEMM256_CORE(APTR, BPTR, KT, KOFF, NG_)                                       \
  const int lane = tid & 63, wv = tid >> 6;                                           \
  const int l16 = lane & 15, quad = lane >> 4;                                        \
  const int wr = wv >> 2, wc = wv & 3;                                                \
  const int srow = tid >> 3;                                                          \
  const int scc = (tid & 7) ^ (srow & 7);                                             \
  const unsigned short* Asrc = (APTR) + (size_t)(bm + srow) * (KT) + (KOFF) + scc * 8;\
  const unsigned short* Bsrc = (BPTR) + (size_t)(bn + srow) * (KT) + (KOFF) + scc * 8;\
  auto stageKstep = [&](int buf, int kk) {                                            \
    char* dA = smem + buf * 65536;                                                    \
    char* dB = dA + 32768;                                                            \
    _Pragma("unroll")                                                                 \
    for (int h = 0; h < 2; h++)                                                       \
      _Pragma("unroll")                                                               \
      for (int j = 0; j < 2; j++) {                                                   \
        async16(Asrc + (size_t)(h * 128 + 64 * j) * (KT) + kk,                        \
                dA + h * 16384 + (j * 512 + tid) * 16);                               \
        async16(Bsrc + (size_t)(h * 128 + 64 * j) * (KT) + kk,                        \
                dB + h * 16384 + (j * 512 + tid) * 16);                               \
      }                                                                               \
  };                                                                                  \
  floatx4 acc[8][4] = {};                                                             \
  stageKstep(0, 0);                                                                   \
  __builtin_amdgcn_s_waitcnt(WAITCNT_VM0);                                            \
  __builtin_amdgcn_s_barrier();                                                       \
  for (int g = 0; g < (NG_); g++) {                                                   \
    const int p = g & 1;                                                              \
    const char* Ab = smem + p * 65536 + wr * 16384;                                   \
    const char* Bb = smem + p * 65536 + 32768 + (wc >> 1) * 16384;                    \
    bf16x8 bg[4][2];                                                                  \
    _Pragma("unroll")                                                                 \
    for (int q = 0; q < 4; q++) {                                                     \
      if (q == 0) {                                                                   \
        if (g + 1 < (NG_)) stageKstep(p ^ 1, (g + 1) << 6);                           \
        _Pragma("unroll")                                                             \
        for (int ni = 0; ni < 4; ni++) {                                              \
          const int lr = (wc & 1) * 64 + ni * 16 + l16;                               \
          _Pragma("unroll")                                                           \
          for (int ks = 0; ks < 2; ks++)                                              \
            bg[ni][ks] = *(const bf16x8*)(Bb + lr * 128 +                             \
                                          (((quad + 4 * ks) ^ (lr & 7)) * 16));       \
        }                                                                             \
      }                                                                               \
      bf16x8 af[2][2];                                                                \
      _Pragma("unroll")                                                               \
      for (int m = 0; m < 2; m++) {                                                   \
        const int lr = (q * 2 + m) * 16 + l16;                                        \
        _Pragma("unroll")                                                             \
        for (int ks = 0; ks < 2; ks++)                                                \
          af[m][ks] = *(const bf16x8*)(Ab + lr * 128 +                                \
                                       (((quad + 4 * ks) ^ (lr & 7)) * 16));          \
      }                                                                               \
      __builtin_amdgcn_s_barrier();                                                   \
      __builtin_amdgcn_s_waitcnt(WAITCNT_LGKM0);                                      \
      __builtin_amdgcn_s_setprio(1);                                                  \
      _Pragma("unroll")                                                               \
      for (int ks = 0; ks < 2; ks++)                                                  \
        _Pragma("unroll")                                                             \
        for (int ni = 0; ni < 4; ni++)                                                \
          _Pragma("unroll")                                                           \
          for (int m = 0; m < 2; m++)                                                 \
            acc[q * 2 + m][ni] = __builtin_amdgcn_mfma_f32_16x16x32_bf16(             \
                af[m][ks], bg[ni][ks], acc[q * 2 + m][ni], 0, 0, 0);                  \
      __builtin_amdgcn_s_setprio(0);                                                  \
      if (q == 3) __builtin_amdgcn_s_waitcnt(WAITCNT_VM0);                            \
      __builtin_amdgcn_s_barrier();                                                   \
    }                                                                                 \
  }

// -------- W1 GEMM: hb = gelu(x1b @ W1T^T + b1) bf16 (proven r6 kernel, unchanged) --------
__global__ __launch_bounds__(512, 2) void gemm256g(const unsigned short* __restrict__ A,
                                                   const unsigned short* __restrict__ Bt,
                                                   const float* __restrict__ bias,
                                                   unsigned short* __restrict__ Cout,
                                                   int M, int N, int K) {
  extern __shared__ char smem[];  // 131072
  const int tid = threadIdx.x;
  int bxx = blockIdx.x, byy = blockIdx.y;
  {  // XCD 2D tiling: each XCD gets a 4x8 region
    const int id = byy * 16 + bxx;
    const int xcd = id & 7, sub = id >> 3;
    bxx = (xcd & 3) * 4 + (sub & 3);
    byy = (xcd >> 2) * 8 + (sub >> 2);
  }
  const int bm = byy * 256, bn = bxx * 256;
  GEMM256_CORE(A, Bt, K, 0, K >> 6)

  // epilogue: gelu + bias -> bf16, coalesced via per-wave 16x64 LDS transpose tile
  __syncthreads();
  unsigned short* eb = (unsigned short*)smem + wv * 1152;  // 16 rows x 72 shorts
  float bvv[4];
#pragma unroll
  for (int ni = 0; ni < 4; ni++) bvv[ni] = bias[bn + wc * 64 + ni * 16 + l16];
  const int lrow = lane >> 2, ck = lane & 3;
#pragma unroll
  for (int mi = 0; mi < 8; mi++) {
#pragma unroll
    for (int ni = 0; ni < 4; ni++)
#pragma unroll
      for (int r = 0; r < 4; r++)
        eb[(quad * 4 + r) * 72 + ni * 16 + l16] =
            f2bf(gelu_f(acc[mi][ni][r] + bvv[ni]));
    __syncthreads();
    unsigned short* gp =
        Cout + (size_t)(bm + wr * 128 + mi * 16 + lrow) * N + bn + wc * 64;
#pragma unroll
    for (int j = 0; j < 2; j++)
      *(uint4*)(gp + j * 32 + ck * 8) = *(const uint4*)&eb[lrow * 72 + j * 32 + ck * 8];
    __syncthreads();
  }
}

// -------- QKV GEMM on the 256^2 template: C[4096,3072] split-written as bf16 Q/K/V^T --------
// Q pre-scaled by 1/sqrt(hd)*log2(e). Grid 12x16 = 192 blocks (all resident, 0.75/CU);
// XCD tiling: per XCD a 3bx x 8by region (B-panel 1.5 MB L2-resident).
__global__ __launch_bounds__(512, 2) void gemm256_qkv(const unsigned short* __restrict__ A,
                                                      const unsigned short* __restrict__ Bt,
                                                      const float* __restrict__ bias,
                                                      unsigned short* __restrict__ Qg,
                                                      unsigned short* __restrict__ Kg,
                                                      unsigned short* __restrict__ Vtg) {
  extern __shared__ char smem[];  // 131072
  const int tid = threadIdx.x;
  const int id = blockIdx.y * 12 + blockIdx.x;  // 0..191, x fastest
  const int xcd = id / 24, sub = id % 24;
  const int bxx = (xcd & 3) * 3 + sub % 3;      // 0..11
  const int byy = (xcd >> 2) * 8 + sub / 3;     // 0..15
  const int bm = byy * 256, bn = bxx * 256;
  GEMM256_CORE(A, Bt, 1024, 0, 16)

  const float QSCALE = 0.125f * 1.44269504089f;  // 1/sqrt(64) * log2(e)
#pragma unroll
  for (int ni = 0; ni < 4; ni++) {
    const int col = bn + wc * 64 + ni * 16 + l16;   // 0..3071
    const float bv = bias[col];
    const int sec = col >> 10;                 // 0=q 1=k 2=v
    const int cc = col & 1023;
    const int hh = cc >> 6, dd = cc & 63;
#pragma unroll
    for (int mi = 0; mi < 8; mi++) {
      const int row0 = bm + wr * 128 + mi * 16 + quad * 4;   // token row (0..4095)
      const int b2 = row0 >> 11, tt0 = row0 & 2047;
      if (sec == 0) {
        unsigned short* q = Qg + ((size_t)(b2 * HEADS + hh) * TSEQ + tt0) * HD + dd;
#pragma unroll
        for (int r = 0; r < 4; r++)
          q[(size_t)r * HD] = f2bf((acc[mi][ni][r] + bv) * QSCALE);
      } else if (sec == 1) {
        unsigned short* k = Kg + ((size_t)(b2 * HEADS + hh) * TSEQ + tt0) * HD + dd;
#pragma unroll
        for (int r = 0; r < 4; r++)
          k[(size_t)r * HD] = f2bf(acc[mi][ni][r] + bv);
      } else {
        ushort4 o;
        o.x = f2bf(acc[mi][ni][0] + bv);
        o.y = f2bf(acc[mi][ni][1] + bv);
        o.z = f2bf(acc[mi][ni][2] + bv);
        o.w = f2bf(acc[mi][ni][3] + bv);
        *(ushort4*)(Vtg + ((size_t)(b2 * HEADS + hh) * HD + dd) * TSEQ + tt0) = o;
      }
    }
  }
}

// -------- split-K GEMM on the 256^2 template: Cp[z][M,N] fp32 partials --------
// Grid 4x16x4 = 256 blocks = 1/CU. Used for Wout (Ktot=1024, Ksl=256, NG=4) and
// W2 (Ktot=4096, Ksl=1024, NG=16). XCD mapping: 32 contiguous (bx,by) per XCD at
// one z (B K-chunk <= 2 MB L2-resident).
__global__ __launch_bounds__(512, 2) void gemm256_sk(const unsigned short* __restrict__ A,
                                                     const unsigned short* __restrict__ Bt,
                                                     float* __restrict__ Cp,
                                                     int M, int N, int Ktot, int Ksl) {
  extern __shared__ char smem[];  // 131072
  const int tid = threadIdx.x;
  const int id = (blockIdx.z * 16 + blockIdx.y) * 4 + blockIdx.x;  // 0..255
  const int xcd = id >> 5, sub = id & 31;
  const int bxx = sub & 3;
  const int u = xcd * 8 + (sub >> 2);   // 0..63
  const int byy = u & 15, bz = u >> 4;
  const int bm = byy * 256, bn = bxx * 256;
  const int koff = bz * Ksl;
  GEMM256_CORE(A, Bt, Ktot, koff, Ksl >> 6)

  float* out = Cp + (size_t)bz * M * (size_t)N;
#pragma unroll
  for (int ni = 0; ni < 4; ni++) {
    const int col = bn + wc * 64 + ni * 16 + l16;
#pragma unroll
    for (int mi = 0; mi < 8; mi++) {
      const int row0 = bm + wr * 128 + mi * 16 + quad * 4;
#pragma unroll
      for (int r = 0; r < 4; r++)
        out[(size_t)(row0 + r) * N + col] = acc[mi][ni][r];
    }
  }
}

// ---------------- MFMA flash attention (r6-proven, unchanged) ----------------
__global__ __launch_bounds__(256, 4) void attn_mfma(const unsigned short* __restrict__ Qg,
                                                    const unsigned short* __restrict__ Kg,
                                                    const unsigned short* __restrict__ Vtg,
                                                    unsigned short* __restrict__ ob) {
  __shared__ __align__(16) char smem[40960];
  unsigned short* QPs = (unsigned short*)smem;  // 8KB: Q stage, then 4x 1152B P tiles

  // XCD-aware swizzle: each XCD gets 128 consecutive logical tiles = 4 (b,h) groups.
  const int bid = blockIdx.x;
  const int lid = (bid & 7) * 128 + (bid >> 3);
  const int qt = lid & 31;          // 32 query-tiles of 64 per (b,h)
  const int h = (lid >> 5) & 15;
  const int b = lid >> 9;
  const int tid = threadIdx.x;
  const int w = tid >> 6, lane = tid & 63, l16 = lane & 15, quad = lane >> 4;
  const int qg = w >> 1;   // query group: rows qg*32 .. qg*32+31
  const int kh = w & 1;    // key half: keys kh*32 .. kh*32+31 of each chunk

  const int r0 = tid >> 3;                 // 0..31
  const int c0 = (tid & 7) ^ (r0 & 7);     // swizzled 16B chunk

  const char* Qbase = (const char*)(Qg + ((size_t)(b * HEADS + h) * TSEQ + qt * 64) * HD);
  const char* Kbase = (const char*)(Kg + (size_t)(b * HEADS + h) * TSEQ * HD);
  const char* Vbase = (const char*)(Vtg + (size_t)(b * HEADS + h) * HD * TSEQ);

  auto Ksp = [&](int s) -> char* { return smem + 8192 + s * 8192; };
  auto Vsp = [&](int s) -> char* { return smem + 24576 + s * 8192; };

  auto issueKV = [&](int s, int ch) {
    const size_t koff = (size_t)ch * 64;
#pragma unroll
    for (int i = 0; i < 2; i++) {
      async16(Kbase + (koff + r0 + i * 32) * 128 + c0 * 16, Ksp(s) + (i * 256 + tid) * 16);
      async16(Vbase + (size_t)(r0 + i * 32) * (TSEQ * 2) + koff * 2 + c0 * 16,
              Vsp(s) + (i * 256 + tid) * 16);
    }
  };

  // stage Q (2 loads/thread) then K/V chunks 0,1 (4 loads/thread each)
#pragma unroll
  for (int i = 0; i < 2; i++)
    async16(Qbase + (size_t)(r0 + i * 32) * 128 + c0 * 16, (char*)QPs + (i * 256 + tid) * 16);
  issueKV(0, 0);
  issueKV(1, 1);

  __builtin_amdgcn_s_waitcnt(WAITCNT_VM8);  // Q (oldest 2) done; 8 KV stay in flight
  __builtin_amdgcn_s_barrier();

  // preload Q a-fragments (rows of this wave's query group)
  bf16x8 qf[2][2];
#pragma unroll
  for (int mi = 0; mi < 2; mi++)
#pragma unroll
    for (int kt = 0; kt < 2; kt++) {
      const int row = qg * 32 + mi * 16 + l16;
      qf[mi][kt] = *(const bf16x8*)((const char*)QPs + row * 128 +
                                    (((quad + 4 * kt) ^ (row & 7)) * 16));
    }
  // Q reads must land before ANY wave's P writes overlay this region (cross-wave WAR)
  __builtin_amdgcn_s_waitcnt(WAITCNT_LGKM0);
  __builtin_amdgcn_sched_barrier(0);

  union { unsigned short u[8]; bf16x8 b; } onesu;
#pragma unroll
  for (int j = 0; j < 8; j++) onesu.u[j] = 0x3F80;  // bf16 1.0
  const bf16x8 ones = onesu.b;

  floatx4 oacc[2][5] = {};            // [mi][nj]; nj==4 accumulates the row sum l
  char* Pw = (char*)QPs + w * 1152;   // wave-private 16x32 bf16 P tile, 72B rows

  const int NC = TSEQ / 64;
  int sidx = 0;
  for (int ch = 0; ch < NC; ch++) {
    if (ch < NC - 1) __builtin_amdgcn_s_waitcnt(WAITCNT_VM4);
    else             __builtin_amdgcn_s_waitcnt(WAITCNT_VM0);
    __builtin_amdgcn_s_barrier();   // all waves' DMA for chunk ch landed

    // S = Q K_half^T (scale+log2e folded into Q)
    floatx4 sacc[2][2] = {};
    __builtin_amdgcn_s_setprio(1);
#pragma unroll
    for (int kt = 0; kt < 2; kt++) {
#pragma unroll
      for (int ni = 0; ni < 2; ni++) {
        const int krow = kh * 32 + ni * 16 + l16;
        bf16x8 kf = *(const bf16x8*)(Ksp(sidx) + krow * 128 +
                                     (((quad + 4 * kt) ^ (krow & 7)) * 16));
#pragma unroll
        for (int mi = 0; mi < 2; mi++)
          sacc[mi][ni] =
              __builtin_amdgcn_mfma_f32_16x16x32_bf16(qf[mi][kt], kf, sacc[mi][ni], 0, 0, 0);
      }
    }
    __builtin_amdgcn_s_setprio(0);

    // P = 2^S; per-mi: write 16-row tile (truncating bf16, conflict-free 72B stride),
    // then read this mi's A-fragments back. Buffer reused across mi.
    bf16x8 pf[2];
#pragma unroll
    for (int mi = 0; mi < 2; mi++) {
#pragma unroll
      for (int ni = 0; ni < 2; ni++)
#pragma unroll
        for (int r = 0; r < 4; r++) {
          const float p = exp2_fast(sacc[mi][ni][r]);
          const unsigned int pu = __builtin_bit_cast(unsigned int, p);
          *((unsigned short*)(Pw + (quad * 4 + r) * 72 + (ni * 16 + l16) * 2)) =
              (unsigned short)(pu >> 16);
        }
      union { bf16x8 v8; bf16x4 v4[2]; } u;
      u.v4[0] = *(const bf16x4*)(Pw + l16 * 72 + quad * 16);
      u.v4[1] = *(const bf16x4*)(Pw + l16 * 72 + quad * 16 + 8);
      pf[mi] = u.v8;
    }

    // O += P V_half ; l += P 1   (k = 32 keys: single MFMA k-depth)
    __builtin_amdgcn_s_setprio(1);
#pragma unroll
    for (int nj = 0; nj < 4; nj++) {
      const int vrow = nj * 16 + l16;
      bf16x8 vf = *(const bf16x8*)(Vsp(sidx) + vrow * 128 +
                                   (((quad + 4 * kh) ^ (vrow & 7)) * 16));
#pragma unroll
      for (int mi = 0; mi < 2; mi++)
        oacc[mi][nj] = __builtin_amdgcn_mfma_f32_16x16x32_bf16(pf[mi], vf, oacc[mi][nj], 0, 0, 0);
    }
#pragma unroll
    for (int mi = 0; mi < 2; mi++)
      oacc[mi][4] = __builtin_amdgcn_mfma_f32_16x16x32_bf16(pf[mi], ones, oacc[mi][4], 0, 0, 0);
    __builtin_amdgcn_s_setprio(0);

    // drain this wave's DS reads (keep DMA in flight), then allow stage reuse
    __builtin_amdgcn_s_waitcnt(WAITCNT_LGKM0);
    __builtin_amdgcn_s_barrier();
    if (ch + 2 < NC) issueKV(sidx, ch + 2);
    sidx ^= 1;
  }

  // ---- key-half combine: kh=1 waves stage partials, kh=0 waves reduce+store ----
  __syncthreads();  // all stages dead; smem reusable
  float* Op = (float*)smem + qg * (32 * 66);  // 32 rows x 66 floats (64 O + 1 l + pad)
  if (kh == 1) {
#pragma unroll
    for (int mi = 0; mi < 2; mi++)
#pragma unroll
      for (int r = 0; r < 4; r++) {
        const int row = mi * 16 + quad * 4 + r;
#pragma unroll
        for (int nj = 0; nj < 4; nj++)
          Op[row * 66 + nj * 16 + l16] = oacc[mi][nj][r];
        if (l16 == 0) Op[row * 66 + 64] = oacc[mi][4][r];
      }
  }
  __syncthreads();
  if (kh == 0) {
#pragma unroll
    for (int mi = 0; mi < 2; mi++)
#pragma unroll
      for (int r = 0; r < 4; r++) {
        const int row = mi * 16 + quad * 4 + r;
        const float inv = 1.0f / (oacc[mi][4][r] + Op[row * 66 + 64]);
        const int t = qt * 64 + qg * 32 + row;
        unsigned short* orow = ob + (size_t)(b * TSEQ + t) * DIM + h * HD + l16;
#pragma unroll
        for (int nj = 0; nj < 4; nj++)
          orow[nj * 16] = f2bf((oacc[mi][nj][r] + Op[row * 66 + nj * 16 + l16]) * inv);
      }
  }
}

// ------- x_out = x_in + LN( sum_p parts[p] + bias ; g, b ); optional bf16 copy -------
template <int NP, int WBF>
__global__ __launch_bounds__(256) void add_ln_red(const float* __restrict__ xin,
                                                  const float* __restrict__ parts,
                                                  const float* __restrict__ bias,
                                                  const float* __restrict__ gw,
                                                  const float* __restrict__ bw,
                                                  float* __restrict__ xout,
                                                  unsigned short* __restrict__ xbf) {
  const size_t MN = (size_t)4096 * DIM;
  const int row = blockIdx.x;
  const int tid = threadIdx.x;
  const int c = tid * 4;
  const size_t base = (size_t)row * DIM;
  float4 v = *(const float4*)(parts + base + c);
#pragma unroll
  for (int p = 1; p < NP; p++) {
    float4 t = *(const float4*)(parts + p * MN + base + c);
    v.x += t.x; v.y += t.y; v.z += t.z; v.w += t.w;
  }
  float4 bb = *(const float4*)(bias + c);
  v.x += bb.x; v.y += bb.y; v.z += bb.z; v.w += bb.w;

  float s = v.x + v.y + v.z + v.w;
  float s2 = v.x * v.x + v.y * v.y + v.z * v.z + v.w * v.w;
#pragma unroll
  for (int off = 1; off < 64; off <<= 1) {
    s += __shfl_xor(s, off);
    s2 += __shfl_xor(s2, off);
  }
  __shared__ float rsum[4], rsq[4];
  if ((tid & 63) == 0) { rsum[tid >> 6] = s; rsq[tid >> 6] = s2; }
  __syncthreads();
  s = rsum[0] + rsum[1] + rsum[2] + rsum[3];
  s2 = rsq[0] + rsq[1] + rsq[2] + rsq[3];
  const float mu = s * (1.0f / DIM);
  const float var = s2 * (1.0f / DIM) - mu * mu;
  const float rstd = rsqrtf(var + EPS);
  float4 xv = *(const float4*)(xin + base + c);
  float4 gv = *(const float4*)(gw + c);
  float4 bv = *(const float4*)(bw + c);
  float4 o;
  o.x = xv.x + (v.x - mu) * rstd * gv.x + bv.x;
  o.y = xv.y + (v.y - mu) * rstd * gv.y + bv.y;
  o.z = xv.z + (v.z - mu) * rstd * gv.z + bv.z;
  o.w = xv.w + (v.w - mu) * rstd * gv.w + bv.w;
  *(float4*)(xout + base + c) = o;
  if (WBF) {
    ushort4 ob;
    ob.x = f2bf(o.x); ob.y = f2bf(o.y); ob.z = f2bf(o.z); ob.w = f2bf(o.w);
    *(ushort4*)(xbf + base + c) = ob;
  }
}

extern "C" void kernel_launch(void* const* d_in, const int* in_sizes, int n_in,
                              void* d_out, int out_size, void* d_ws, size_t ws_size,
                              hipStream_t stream) {
  const float* x    = (const float*)d_in[0];
  const float* Wqkv = (const float*)d_in[1];
  const float* bqkv = (const float*)d_in[2];
  const float* Wout = (const float*)d_in[3];
  const float* bout = (const float*)d_in[4];
  const float* W1   = (const float*)d_in[5];
  const float* b1   = (const float*)d_in[6];
  const float* W2   = (const float*)d_in[7];
  const float* b2   = (const float*)d_in[8];
  const float* g1   = (const float*)d_in[9];
  const float* be1  = (const float*)d_in[10];
  const float* g2   = (const float*)d_in[11];
  const float* be2  = (const float*)d_in[12];

  static bool s_attr = false;
  if (!s_attr) {
    hipFuncSetAttribute((const void*)gemm256g,
                        hipFuncAttributeMaxDynamicSharedMemorySize, 131072);
    hipFuncSetAttribute((const void*)gemm256_qkv,
                        hipFuncAttributeMaxDynamicSharedMemorySize, 131072);
    hipFuncSetAttribute((const void*)gemm256_sk,
                        hipFuncAttributeMaxDynamicSharedMemorySize, 131072);
    s_attr = true;
  }

  char* w = (char*)d_ws;
  const size_t MB = 1048576;
  // Liveness-checked layout (max 160 MB):
  unsigned short* xb     = (unsigned short*)(w + 0 * MB);    //  8 MB  (dead after qkv)
  unsigned short* WqkvT  = (unsigned short*)(w + 8 * MB);    //  6 MB  (dead after qkv)
  unsigned short* WoutT  = (unsigned short*)(w + 14 * MB);   //  2 MB  (dead after Wout gemm)
  unsigned short* W1T    = (unsigned short*)(w + 16 * MB);   //  8 MB  (dead after W1 gemm)
  unsigned short* W2T    = (unsigned short*)(w + 24 * MB);   //  8 MB
  unsigned short* Qb     = (unsigned short*)(w + 32 * MB);   //  8 MB  (dead after attn)
  unsigned short* Kb     = (unsigned short*)(w + 40 * MB);   //  8 MB  (dead after attn)
  unsigned short* Vtb    = (unsigned short*)(w + 48 * MB);   // 16 MB  (dead after attn)
  unsigned short* obuf   = (unsigned short*)(w + 64 * MB);   //  8 MB  (dead after Wout gemm)
  float*          atno_p = (float*)(w + 72 * MB);            // 64 MB  Wout partials x4 (dead after ln1)
  float*          x1     = (float*)(w + 136 * MB);           // 16 MB
  unsigned short* x1b    = (unsigned short*)(w + 152 * MB);  //  8 MB
  unsigned short* hb     = (unsigned short*)(w + 32 * MB);   // 32 MB  (reuses Qb/Kb/Vtb)
  float*          ffn_p  = (float*)(w + 72 * MB);            // 64 MB  W2 partials x4 (reuses atno_p)

  // fused prep: x cvt (4096 blocks) + 4 transposes (12288 tiles)
  prep_all<<<16384, 256, 0, stream>>>(x, Wqkv, Wout, W1, W2, xb, WqkvT, WoutT, W1T, W2T);

  // qkv = x @ Wqkv + bqkv -> bf16 Q (pre-scaled incl. log2e), K, V^T; 256^2 template
  gemm256_qkv<<<dim3(12, 16), 512, 131072, stream>>>(xb, WqkvT, bqkv, Qb, Kb, Vtb);
  // MFMA flash attention -> o (bf16); 1024 XCD-swizzled blocks, 4/CU, key-split waves
  attn_mfma<<<1024, 256, 0, stream>>>(Qb, Kb, Vtb, obuf);
  // attn_out partials = o @ Wout (256^2 split-K 4: 256 blocks = 1/CU, Ksl=256)
  gemm256_sk<<<dim3(4, 16, 4), 512, 131072, stream>>>(obuf, WoutT, atno_p, 4096, 1024, 1024, 256);
  // x1 = x + LN(p0..p3 + bout)
  add_ln_red<4, 1><<<4096, 256, 0, stream>>>(x, atno_p, bout, g1, be1, x1, x1b);
  // h = gelu(x1 @ W1 + b1) -> bf16; 256^2 8-phase GEMM, 256 blocks = 1/CU
  gemm256g<<<dim3(16, 16), 512, 131072, stream>>>(x1b, W1T, b1, hb, 4096, 4096, 1024);
  // ffn partials = h @ W2 (256^2 split-K 4: 256 blocks = 1/CU, Ksl=1024)
  gemm256_sk<<<dim3(4, 16, 4), 512, 131072, stream>>>(hb, W2T, ffn_p, 4096, 1024, 4096, 1024);
  // out = x1 + LN(p0..p3 + b2)
  add_ln_red<4, 0><<<4096, 256, 0, stream>>>(x1, ffn_p, b2, g2, be2, (float*)d_out, nullptr);
}

// Round 8
// 345.243 us; speedup vs baseline: 1.0506x; 1.0506x over previous
//
#include <hip/hip_runtime.h>
#include <cstdint>
#include <cstddef>

#define DIM 1024
#define HEADS 16
#define HD 64
#define DFF 4096
#define TSEQ 2048
#define EPS 1e-5f

// s_waitcnt immediates: vmcnt bits[3:0]|[15:14], expcnt bits[6:4], lgkmcnt bits[11:8]
#define WAITCNT_VM4 0xF74        // vmcnt=4, lgkm=15 (no wait)
#define WAITCNT_VM0 0xF70        // vmcnt=0, lgkm=15
#define WAITCNT_VM8 0xF78        // vmcnt=8, lgkm=15
#define WAITCNT_LGKM0 0xC07F     // lgkm=0, vmcnt=63 (no wait) -- drain DS, keep DMA in flight

typedef __bf16 bf16x8 __attribute__((ext_vector_type(8)));
typedef __bf16 bf16x4 __attribute__((ext_vector_type(4)));
typedef float floatx4 __attribute__((ext_vector_type(4)));

__device__ __forceinline__ unsigned short f2bf(float f) {
  union { float f; unsigned int u; } v; v.f = f;
  return (unsigned short)((v.u + 0x7FFFu + ((v.u >> 16) & 1u)) >> 16);
}

// raw v_exp_f32: computes 2^x (log2e is pre-folded into the Q scale)
__device__ __forceinline__ float exp2_fast(float x) {
#if __has_builtin(__builtin_amdgcn_exp2f)
  return __builtin_amdgcn_exp2f(x);
#else
  float r;
  asm("v_exp_f32 %0, %1" : "=v"(r) : "v"(x));
  return r;
#endif
}

// tanh-form GELU: max |err| vs exact-erf gelu ~3e-3 (negligible vs bf16 path noise)
__device__ __forceinline__ float gelu_f(float v) {
  const float u = v * (0.7978845608f + 0.0356774081f * v * v);
  const float e = __expf(2.0f * u);
  const float t = 1.0f - 2.0f / (e + 1.0f);
  return 0.5f * v * (1.0f + t);
}

__device__ __forceinline__ void async16(const void* g, void* l) {
  __builtin_amdgcn_global_load_lds(
      (const __attribute__((address_space(1))) void*)g,
      (__attribute__((address_space(3))) void*)l, 16, 0, 0);
}

// ---------------- fused prep: x->bf16 + 4 weight transposes (one launch) ----------------
__global__ __launch_bounds__(256) void prep_all(const float* __restrict__ x,
                                                const float* __restrict__ Wqkv,
                                                const float* __restrict__ Wout,
                                                const float* __restrict__ W1,
                                                const float* __restrict__ W2,
                                                unsigned short* __restrict__ xb,
                                                unsigned short* __restrict__ WqkvT,
                                                unsigned short* __restrict__ WoutT,
                                                unsigned short* __restrict__ W1T,
                                                unsigned short* __restrict__ W2T) {
  const int bid = blockIdx.x;
  const int tid = threadIdx.x;
  if (bid < 4096) {  // x -> bf16, float4 per thread
    const int i = bid * 256 + tid;
    float4 v = ((const float4*)x)[i];
    ushort4 o;
    o.x = f2bf(v.x); o.y = f2bf(v.y); o.z = f2bf(v.z); o.w = f2bf(v.w);
    ((ushort4*)xb)[i] = o;
    return;
  }
  int id = bid - 4096;
  const float* src; unsigned short* dst; int R, C, gx;
  if (id < 3072)      {            src = Wqkv; dst = WqkvT; R = 1024; C = 3072; gx = 96; }
  else if (id < 4096) { id -= 3072; src = Wout; dst = WoutT; R = 1024; C = 1024; gx = 32; }
  else if (id < 8192) { id -= 4096; src = W1;   dst = W1T;   R = 1024; C = 4096; gx = 128; }
  else                { id -= 8192; src = W2;   dst = W2T;   R = 4096; C = 1024; gx = 32; }
  const int c0 = (id % gx) * 32, r0 = (id / gx) * 32;
  const int tx = tid & 31, ty = tid >> 5;  // 32 x 8
  __shared__ float tile[32][33];
#pragma unroll
  for (int i = 0; i < 32; i += 8)
    tile[ty + i][tx] = src[(size_t)(r0 + ty + i) * C + c0 + tx];
  __syncthreads();
#pragma unroll
  for (int i = 0; i < 32; i += 8)
    dst[(size_t)(c0 + ty + i) * R + r0 + tx] = f2bf(tile[tx][ty + i]);
}

// ====== 3-stage K-loop (48 KB LDS, prefetch distance 2, 1 barrier/iter) ======
// Distance-2 prefetch fully covers HBM/L2 latency; used by the 128^2 split-K kernels
// (both measured <=60 us at this structure in r6).
#define PIPELINED_KLOOP3(NIT)                                                        \
  auto issue = [&](int s, int k0) {                                                  \
    async16(Ab0 + k0, &lds[s][tid * 8]);                                             \
    async16(Ab1 + k0, &lds[s][2048 + tid * 8]);                                      \
    async16(Bb0 + k0, &lds[s][4096 + tid * 8]);                                      \
    async16(Bb1 + k0, &lds[s][6144 + tid * 8]);                                      \
  };                                                                                 \
  issue(0, 0);                                                                       \
  issue(1, 32);                                                                      \
  int sidx = 0;                                                                      \
  for (int k = 0; k < (NIT); k++) {                                                  \
    if (k < (NIT)-1) __builtin_amdgcn_s_waitcnt(WAITCNT_VM4);                        \
    else             __builtin_amdgcn_s_waitcnt(WAITCNT_VM0);                        \
    __builtin_amdgcn_s_barrier();                                                    \
    if (k + 2 < (NIT)) {                                                             \
      int s2 = sidx + 2; if (s2 >= 3) s2 -= 3;                                       \
      issue(s2, (k + 2) * 32);                                                       \
    }                                                                                \
    bf16x8 af[4], bg[4];                                                             \
    _Pragma("unroll")                                                                \
    for (int mi = 0; mi < 4; mi++)                                                   \
      af[mi] = *(const bf16x8*)&lds[sidx][(wm + mi * 16 + l16) * 32 + quad * 8];     \
    _Pragma("unroll")                                                                \
    for (int ni = 0; ni < 4; ni++)                                                   \
      bg[ni] = *(const bf16x8*)&lds[sidx][4096 + (wn + ni * 16 + l16) * 32 + quad * 8]; \
    _Pragma("unroll")                                                                \
    for (int mi = 0; mi < 4; mi++)                                                   \
      _Pragma("unroll")                                                              \
      for (int ni = 0; ni < 4; ni++)                                                 \
        acc[mi][ni] =                                                                \
            __builtin_amdgcn_mfma_f32_16x16x32_bf16(af[mi], bg[ni], acc[mi][ni], 0, 0, 0); \
    sidx = (sidx == 2) ? 0 : sidx + 1;                                               \
  }

// ============ 256x256-tile 8-phase GEMM core (m201-template; harness-proven r6) ============
// 512 threads = 8 waves (2M x 4N); per-wave output 128x64 (acc[8][4]); BK=64/K-step,
// 64 MFMA/wave/K-step in 4 phases x 16 MFMA. LDS 128 KiB: 2 K-step buffers x
// (A 256x64 | B 256x64), swizzled chunk^(row&7) (linear DMA dest + pre-swizzled global
// source + XOR on read). ph0 issues ALL next-K-step staging; each phase {af ds_reads ->
// barrier -> lgkm0 -> setprio -> 16 MFMA -> setprio -> barrier}; vmcnt(0) only at ph3.
// Declares/leaves in scope: lane,wv,l16,quad,wr,wc and acc[8][4] for the epilogue.
#define GEMM256_CORE(APTR, BPTR, KT, KOFF, NG_)                                       \
  const int lane = tid & 63, wv = tid >> 6;                                           \
  const int l16 = lane & 15, quad = lane >> 4;                                        \
  const int wr = wv >> 2, wc = wv & 3;                                                \
  const int srow = tid >> 3;                                                          \
  const int scc = (tid & 7) ^ (srow & 7);                                             \
  const unsigned short* Asrc = (APTR) + (size_t)(bm + srow) * (KT) + (KOFF) + scc * 8;\
  const unsigned short* Bsrc = (BPTR) + (size_t)(bn + srow) * (KT) + (KOFF) + scc * 8;\
  auto stageKstep = [&](int buf, int kk) {                                            \
    char* dA = smem + buf * 65536;                                                    \
    char* dB = dA + 32768;                                                            \
    _Pragma("unroll")                                                                 \
    for (int h = 0; h < 2; h++)                                                       \
      _Pragma("unroll")                                                               \
      for (int j = 0; j < 2; j++) {                                                   \
        async16(Asrc + (size_t)(h * 128 + 64 * j) * (KT) + kk,                        \
                dA + h * 16384 + (j * 512 + tid) * 16);                               \
        async16(Bsrc + (size_t)(h * 128 + 64 * j) * (KT) + kk,                        \
                dB + h * 16384 + (j * 512 + tid) * 16);                               \
      }                                                                               \
  };                                                                                  \
  floatx4 acc[8][4] = {};                                                             \
  stageKstep(0, 0);                                                                   \
  __builtin_amdgcn_s_waitcnt(WAITCNT_VM0);                                            \
  __builtin_amdgcn_s_barrier();                                                       \
  for (int g = 0; g < (NG_); g++) {                                                   \
    const int p = g & 1;                                                              \
    const char* Ab = smem + p * 65536 + wr * 16384;                                   \
    const char* Bb = smem + p * 65536 + 32768 + (wc >> 1) * 16384;                    \
    bf16x8 bg[4][2];                                                                  \
    _Pragma("unroll")                                                                 \
    for (int q = 0; q < 4; q++) {                                                     \
      if (q == 0) {                                                                   \
        if (g + 1 < (NG_)) stageKstep(p ^ 1, (g + 1) << 6);                           \
        _Pragma("unroll")                                                             \
        for (int ni = 0; ni < 4; ni++) {                                              \
          const int lr = (wc & 1) * 64 + ni * 16 + l16;                               \
          _Pragma("unroll")                                                           \
          for (int ks = 0; ks < 2; ks++)                                              \
            bg[ni][ks] = *(const bf16x8*)(Bb + lr * 128 +                             \
                                          (((quad + 4 * ks) ^ (lr & 7)) * 16));       \
        }                                                                             \
      }                                                                               \
      bf16x8 af[2][2];                                                                \
      _Pragma("unroll")                                                               \
      for (int m = 0; m < 2; m++) {                                                   \
        const int lr = (q * 2 + m) * 16 + l16;                                        \
        _Pragma("unroll")                                                             \
        for (int ks = 0; ks < 2; ks++)                                                \
          af[m][ks] = *(const bf16x8*)(Ab + lr * 128 +                                \
                                       (((quad + 4 * ks) ^ (lr & 7)) * 16));          \
      }                                                                               \
      __builtin_amdgcn_s_barrier();                                                   \
      __builtin_amdgcn_s_waitcnt(WAITCNT_LGKM0);                                      \
      __builtin_amdgcn_s_setprio(1);                                                  \
      _Pragma("unroll")                                                               \
      for (int ks = 0; ks < 2; ks++)                                                  \
        _Pragma("unroll")                                                             \
        for (int ni = 0; ni < 4; ni++)                                                \
          _Pragma("unroll")                                                           \
          for (int m = 0; m < 2; m++)                                                 \
            acc[q * 2 + m][ni] = __builtin_amdgcn_mfma_f32_16x16x32_bf16(             \
                af[m][ks], bg[ni][ks], acc[q * 2 + m][ni], 0, 0, 0);                  \
      __builtin_amdgcn_s_setprio(0);                                                  \
      if (q == 3) __builtin_amdgcn_s_waitcnt(WAITCNT_VM0);                            \
      __builtin_amdgcn_s_barrier();                                                   \
    }                                                                                 \
  }

// -------- W1 GEMM: hb = gelu(x1b @ W1T^T + b1) bf16 (proven r6 kernel, unchanged) --------
__global__ __launch_bounds__(512, 2) void gemm256g(const unsigned short* __restrict__ A,
                                                   const unsigned short* __restrict__ Bt,
                                                   const float* __restrict__ bias,
                                                   unsigned short* __restrict__ Cout,
                                                   int M, int N, int K) {
  extern __shared__ char smem[];  // 131072
  const int tid = threadIdx.x;
  int bxx = blockIdx.x, byy = blockIdx.y;
  {  // XCD 2D tiling: each XCD gets a 4x8 region
    const int id = byy * 16 + bxx;
    const int xcd = id & 7, sub = id >> 3;
    bxx = (xcd & 3) * 4 + (sub & 3);
    byy = (xcd >> 2) * 8 + (sub >> 2);
  }
  const int bm = byy * 256, bn = bxx * 256;
  GEMM256_CORE(A, Bt, K, 0, K >> 6)

  // epilogue: gelu + bias -> bf16, coalesced via per-wave 16x64 LDS transpose tile
  __syncthreads();
  unsigned short* eb = (unsigned short*)smem + wv * 1152;  // 16 rows x 72 shorts
  float bvv[4];
#pragma unroll
  for (int ni = 0; ni < 4; ni++) bvv[ni] = bias[bn + wc * 64 + ni * 16 + l16];
  const int lrow = lane >> 2, ck = lane & 3;
#pragma unroll
  for (int mi = 0; mi < 8; mi++) {
#pragma unroll
    for (int ni = 0; ni < 4; ni++)
#pragma unroll
      for (int r = 0; r < 4; r++)
        eb[(quad * 4 + r) * 72 + ni * 16 + l16] =
            f2bf(gelu_f(acc[mi][ni][r] + bvv[ni]));
    __syncthreads();
    unsigned short* gp =
        Cout + (size_t)(bm + wr * 128 + mi * 16 + lrow) * N + bn + wc * 64;
#pragma unroll
    for (int j = 0; j < 2; j++)
      *(uint4*)(gp + j * 32 + ck * 8) = *(const uint4*)&eb[lrow * 72 + j * 32 + ck * 8];
    __syncthreads();
  }
}

// -------- QKV GEMM on the 256^2 template: C[4096,3072] split-written as bf16 Q/K/V^T --------
// Q pre-scaled by 1/sqrt(hd)*log2(e). Grid 12x16 = 192 blocks (one round, 0.75/CU);
// per-block work identical to a W1 gemm256g block (256x256 out, K=1024) -> time ~ T_W1.
// XCD tiling: per XCD a 3bx x 8by region (B-panel 1.5 MB L2-resident).
__global__ __launch_bounds__(512, 2) void gemm256_qkv(const unsigned short* __restrict__ A,
                                                      const unsigned short* __restrict__ Bt,
                                                      const float* __restrict__ bias,
                                                      unsigned short* __restrict__ Qg,
                                                      unsigned short* __restrict__ Kg,
                                                      unsigned short* __restrict__ Vtg) {
  extern __shared__ char smem[];  // 131072
  const int tid = threadIdx.x;
  const int id = blockIdx.y * 12 + blockIdx.x;  // 0..191, x fastest
  const int xcd = id / 24, sub = id % 24;
  const int bxx = (xcd & 3) * 3 + sub % 3;      // 0..11
  const int byy = (xcd >> 2) * 8 + sub / 3;     // 0..15
  const int bm = byy * 256, bn = bxx * 256;
  GEMM256_CORE(A, Bt, 1024, 0, 16)

  const float QSCALE = 0.125f * 1.44269504089f;  // 1/sqrt(64) * log2(e)
#pragma unroll
  for (int ni = 0; ni < 4; ni++) {
    const int col = bn + wc * 64 + ni * 16 + l16;   // 0..3071
    const float bv = bias[col];
    const int sec = col >> 10;                 // 0=q 1=k 2=v
    const int cc = col & 1023;
    const int hh = cc >> 6, dd = cc & 63;
#pragma unroll
    for (int mi = 0; mi < 8; mi++) {
      const int row0 = bm + wr * 128 + mi * 16 + quad * 4;   // token row (0..4095)
      const int b2 = row0 >> 11, tt0 = row0 & 2047;
      if (sec == 0) {
        unsigned short* q = Qg + ((size_t)(b2 * HEADS + hh) * TSEQ + tt0) * HD + dd;
#pragma unroll
        for (int r = 0; r < 4; r++)
          q[(size_t)r * HD] = f2bf((acc[mi][ni][r] + bv) * QSCALE);
      } else if (sec == 1) {
        unsigned short* k = Kg + ((size_t)(b2 * HEADS + hh) * TSEQ + tt0) * HD + dd;
#pragma unroll
        for (int r = 0; r < 4; r++)
          k[(size_t)r * HD] = f2bf(acc[mi][ni][r] + bv);
      } else {
        ushort4 o;
        o.x = f2bf(acc[mi][ni][0] + bv);
        o.y = f2bf(acc[mi][ni][1] + bv);
        o.z = f2bf(acc[mi][ni][2] + bv);
        o.w = f2bf(acc[mi][ni][3] + bv);
        *(ushort4*)(Vtg + ((size_t)(b2 * HEADS + hh) * HD + dd) * TSEQ + tt0) = o;
      }
    }
  }
}

// ------- split-K GEMM: Cp[z][M,N] = A[:, z*Ksl:(z+1)*Ksl] @ Bt[:, same]^T (fp32) -------
// 128^2 tile, 3-stage loop; 2D XCD tiling over (bx, by, z). r6-proven (<=60 us both uses).
__global__ __launch_bounds__(256) void gemm_splitk(const unsigned short* __restrict__ A,
                                                   const unsigned short* __restrict__ Bt,
                                                   float* __restrict__ Cp,
                                                   int M, int N, int Ktot, int Ksl) {
  __shared__ unsigned short lds[3][8192];
  const int tid = threadIdx.x;
  const int id = (blockIdx.z * 32 + blockIdx.y) * 8 + blockIdx.x;  // linear (x fastest)
  const int xcd = id & 7, sub = id >> 3;
  const int bxx = sub & 7;
  const int byz = xcd * (gridDim.z * 4) + (sub >> 3);  // 32*z/8 = 4z per XCD
  const int byy = byz & 31, bz = byz >> 5;
  const int bm = byy * 128, bn = bxx * 128;
  const int koff = bz * Ksl;
  const int wave = tid >> 6, lane = tid & 63;
  const int l16 = lane & 15, quad = lane >> 4;
  const int wm = (wave >> 1) * 64, wn = (wave & 1) * 64;

  floatx4 acc[4][4] = {};

  const int srow = tid >> 2;
  const int scol = (tid & 3) * 8;

  const unsigned short* Ab0 = A + (size_t)(bm + srow) * Ktot + koff + scol;
  const unsigned short* Ab1 = A + (size_t)(bm + 64 + srow) * Ktot + koff + scol;
  const unsigned short* Bb0 = Bt + (size_t)(bn + srow) * Ktot + koff + scol;
  const unsigned short* Bb1 = Bt + (size_t)(bn + 64 + srow) * Ktot + koff + scol;

  const int nit = Ksl >> 5;
  PIPELINED_KLOOP3(nit)

  float* out = Cp + (size_t)bz * M * (size_t)N;
#pragma unroll
  for (int ni = 0; ni < 4; ni++) {
    const int col = bn + wn + ni * 16 + l16;
#pragma unroll
    for (int mi = 0; mi < 4; mi++) {
      const int row0 = bm + wm + mi * 16 + quad * 4;
#pragma unroll
      for (int r = 0; r < 4; r++)
        out[(size_t)(row0 + r) * N + col] = acc[mi][ni][r];
    }
  }
}

// ---------------- MFMA flash attention (r6-proven, unchanged) ----------------
__global__ __launch_bounds__(256, 4) void attn_mfma(const unsigned short* __restrict__ Qg,
                                                    const unsigned short* __restrict__ Kg,
                                                    const unsigned short* __restrict__ Vtg,
                                                    unsigned short* __restrict__ ob) {
  __shared__ __align__(16) char smem[40960];
  unsigned short* QPs = (unsigned short*)smem;  // 8KB: Q stage, then 4x 1152B P tiles

  // XCD-aware swizzle: each XCD gets 128 consecutive logical tiles = 4 (b,h) groups.
  const int bid = blockIdx.x;
  const int lid = (bid & 7) * 128 + (bid >> 3);
  const int qt = lid & 31;          // 32 query-tiles of 64 per (b,h)
  const int h = (lid >> 5) & 15;
  const int b = lid >> 9;
  const int tid = threadIdx.x;
  const int w = tid >> 6, lane = tid & 63, l16 = lane & 15, quad = lane >> 4;
  const int qg = w >> 1;   // query group: rows qg*32 .. qg*32+31
  const int kh = w & 1;    // key half: keys kh*32 .. kh*32+31 of each chunk

  const int r0 = tid >> 3;                 // 0..31
  const int c0 = (tid & 7) ^ (r0 & 7);     // swizzled 16B chunk

  const char* Qbase = (const char*)(Qg + ((size_t)(b * HEADS + h) * TSEQ + qt * 64) * HD);
  const char* Kbase = (const char*)(Kg + (size_t)(b * HEADS + h) * TSEQ * HD);
  const char* Vbase = (const char*)(Vtg + (size_t)(b * HEADS + h) * HD * TSEQ);

  auto Ksp = [&](int s) -> char* { return smem + 8192 + s * 8192; };
  auto Vsp = [&](int s) -> char* { return smem + 24576 + s * 8192; };

  auto issueKV = [&](int s, int ch) {
    const size_t koff = (size_t)ch * 64;
#pragma unroll
    for (int i = 0; i < 2; i++) {
      async16(Kbase + (koff + r0 + i * 32) * 128 + c0 * 16, Ksp(s) + (i * 256 + tid) * 16);
      async16(Vbase + (size_t)(r0 + i * 32) * (TSEQ * 2) + koff * 2 + c0 * 16,
              Vsp(s) + (i * 256 + tid) * 16);
    }
  };

  // stage Q (2 loads/thread) then K/V chunks 0,1 (4 loads/thread each)
#pragma unroll
  for (int i = 0; i < 2; i++)
    async16(Qbase + (size_t)(r0 + i * 32) * 128 + c0 * 16, (char*)QPs + (i * 256 + tid) * 16);
  issueKV(0, 0);
  issueKV(1, 1);

  __builtin_amdgcn_s_waitcnt(WAITCNT_VM8);  // Q (oldest 2) done; 8 KV stay in flight
  __builtin_amdgcn_s_barrier();

  // preload Q a-fragments (rows of this wave's query group)
  bf16x8 qf[2][2];
#pragma unroll
  for (int mi = 0; mi < 2; mi++)
#pragma unroll
    for (int kt = 0; kt < 2; kt++) {
      const int row = qg * 32 + mi * 16 + l16;
      qf[mi][kt] = *(const bf16x8*)((const char*)QPs + row * 128 +
                                    (((quad + 4 * kt) ^ (row & 7)) * 16));
    }
  // Q reads must land before ANY wave's P writes overlay this region (cross-wave WAR)
  __builtin_amdgcn_s_waitcnt(WAITCNT_LGKM0);
  __builtin_amdgcn_sched_barrier(0);

  union { unsigned short u[8]; bf16x8 b; } onesu;
#pragma unroll
  for (int j = 0; j < 8; j++) onesu.u[j] = 0x3F80;  // bf16 1.0
  const bf16x8 ones = onesu.b;

  floatx4 oacc[2][5] = {};            // [mi][nj]; nj==4 accumulates the row sum l
  char* Pw = (char*)QPs + w * 1152;   // wave-private 16x32 bf16 P tile, 72B rows

  const int NC = TSEQ / 64;
  int sidx = 0;
  for (int ch = 0; ch < NC; ch++) {
    if (ch < NC - 1) __builtin_amdgcn_s_waitcnt(WAITCNT_VM4);
    else             __builtin_amdgcn_s_waitcnt(WAITCNT_VM0);
    __builtin_amdgcn_s_barrier();   // all waves' DMA for chunk ch landed

    // S = Q K_half^T (scale+log2e folded into Q)
    floatx4 sacc[2][2] = {};
    __builtin_amdgcn_s_setprio(1);
#pragma unroll
    for (int kt = 0; kt < 2; kt++) {
#pragma unroll
      for (int ni = 0; ni < 2; ni++) {
        const int krow = kh * 32 + ni * 16 + l16;
        bf16x8 kf = *(const bf16x8*)(Ksp(sidx) + krow * 128 +
                                     (((quad + 4 * kt) ^ (krow & 7)) * 16));
#pragma unroll
        for (int mi = 0; mi < 2; mi++)
          sacc[mi][ni] =
              __builtin_amdgcn_mfma_f32_16x16x32_bf16(qf[mi][kt], kf, sacc[mi][ni], 0, 0, 0);
      }
    }
    __builtin_amdgcn_s_setprio(0);

    // P = 2^S; per-mi: write 16-row tile (truncating bf16, conflict-free 72B stride),
    // then read this mi's A-fragments back. Buffer reused across mi.
    bf16x8 pf[2];
#pragma unroll
    for (int mi = 0; mi < 2; mi++) {
#pragma unroll
      for (int ni = 0; ni < 2; ni++)
#pragma unroll
        for (int r = 0; r < 4; r++) {
          const float p = exp2_fast(sacc[mi][ni][r]);
          const unsigned int pu = __builtin_bit_cast(unsigned int, p);
          *((unsigned short*)(Pw + (quad * 4 + r) * 72 + (ni * 16 + l16) * 2)) =
              (unsigned short)(pu >> 16);
        }
      union { bf16x8 v8; bf16x4 v4[2]; } u;
      u.v4[0] = *(const bf16x4*)(Pw + l16 * 72 + quad * 16);
      u.v4[1] = *(const bf16x4*)(Pw + l16 * 72 + quad * 16 + 8);
      pf[mi] = u.v8;
    }

    // O += P V_half ; l += P 1   (k = 32 keys: single MFMA k-depth)
    __builtin_amdgcn_s_setprio(1);
#pragma unroll
    for (int nj = 0; nj < 4; nj++) {
      const int vrow = nj * 16 + l16;
      bf16x8 vf = *(const bf16x8*)(Vsp(sidx) + vrow * 128 +
                                   (((quad + 4 * kh) ^ (vrow & 7)) * 16));
#pragma unroll
      for (int mi = 0; mi < 2; mi++)
        oacc[mi][nj] = __builtin_amdgcn_mfma_f32_16x16x32_bf16(pf[mi], vf, oacc[mi][nj], 0, 0, 0);
    }
#pragma unroll
    for (int mi = 0; mi < 2; mi++)
      oacc[mi][4] = __builtin_amdgcn_mfma_f32_16x16x32_bf16(pf[mi], ones, oacc[mi][4], 0, 0, 0);
    __builtin_amdgcn_s_setprio(0);

    // drain this wave's DS reads (keep DMA in flight), then allow stage reuse
    __builtin_amdgcn_s_waitcnt(WAITCNT_LGKM0);
    __builtin_amdgcn_s_barrier();
    if (ch + 2 < NC) issueKV(sidx, ch + 2);
    sidx ^= 1;
  }

  // ---- key-half combine: kh=1 waves stage partials, kh=0 waves reduce+store ----
  __syncthreads();  // all stages dead; smem reusable
  float* Op = (float*)smem + qg * (32 * 66);  // 32 rows x 66 floats (64 O + 1 l + pad)
  if (kh == 1) {
#pragma unroll
    for (int mi = 0; mi < 2; mi++)
#pragma unroll
      for (int r = 0; r < 4; r++) {
        const int row = mi * 16 + quad * 4 + r;
#pragma unroll
        for (int nj = 0; nj < 4; nj++)
          Op[row * 66 + nj * 16 + l16] = oacc[mi][nj][r];
        if (l16 == 0) Op[row * 66 + 64] = oacc[mi][4][r];
      }
  }
  __syncthreads();
  if (kh == 0) {
#pragma unroll
    for (int mi = 0; mi < 2; mi++)
#pragma unroll
      for (int r = 0; r < 4; r++) {
        const int row = mi * 16 + quad * 4 + r;
        const float inv = 1.0f / (oacc[mi][4][r] + Op[row * 66 + 64]);
        const int t = qt * 64 + qg * 32 + row;
        unsigned short* orow = ob + (size_t)(b * TSEQ + t) * DIM + h * HD + l16;
#pragma unroll
        for (int nj = 0; nj < 4; nj++)
          orow[nj * 16] = f2bf((oacc[mi][nj][r] + Op[row * 66 + nj * 16 + l16]) * inv);
      }
  }
}

// ------- x_out = x_in + LN( sum_p parts[p] + bias ; g, b ); optional bf16 copy -------
template <int NP, int WBF>
__global__ __launch_bounds__(256) void add_ln_red(const float* __restrict__ xin,
                                                  const float* __restrict__ parts,
                                                  const float* __restrict__ bias,
                                                  const float* __restrict__ gw,
                                                  const float* __restrict__ bw,
                                                  float* __restrict__ xout,
                                                  unsigned short* __restrict__ xbf) {
  const size_t MN = (size_t)4096 * DIM;
  const int row = blockIdx.x;
  const int tid = threadIdx.x;
  const int c = tid * 4;
  const size_t base = (size_t)row * DIM;
  float4 v = *(const float4*)(parts + base + c);
#pragma unroll
  for (int p = 1; p < NP; p++) {
    float4 t = *(const float4*)(parts + p * MN + base + c);
    v.x += t.x; v.y += t.y; v.z += t.z; v.w += t.w;
  }
  float4 bb = *(const float4*)(bias + c);
  v.x += bb.x; v.y += bb.y; v.z += bb.z; v.w += bb.w;

  float s = v.x + v.y + v.z + v.w;
  float s2 = v.x * v.x + v.y * v.y + v.z * v.z + v.w * v.w;
#pragma unroll
  for (int off = 1; off < 64; off <<= 1) {
    s += __shfl_xor(s, off);
    s2 += __shfl_xor(s2, off);
  }
  __shared__ float rsum[4], rsq[4];
  if ((tid & 63) == 0) { rsum[tid >> 6] = s; rsq[tid >> 6] = s2; }
  __syncthreads();
  s = rsum[0] + rsum[1] + rsum[2] + rsum[3];
  s2 = rsq[0] + rsq[1] + rsq[2] + rsq[3];
  const float mu = s * (1.0f / DIM);
  const float var = s2 * (1.0f / DIM) - mu * mu;
  const float rstd = rsqrtf(var + EPS);
  float4 xv = *(const float4*)(xin + base + c);
  float4 gv = *(const float4*)(gw + c);
  float4 bv = *(const float4*)(bw + c);
  float4 o;
  o.x = xv.x + (v.x - mu) * rstd * gv.x + bv.x;
  o.y = xv.y + (v.y - mu) * rstd * gv.y + bv.y;
  o.z = xv.z + (v.z - mu) * rstd * gv.z + bv.z;
  o.w = xv.w + (v.w - mu) * rstd * gv.w + bv.w;
  *(float4*)(xout + base + c) = o;
  if (WBF) {
    ushort4 ob;
    ob.x = f2bf(o.x); ob.y = f2bf(o.y); ob.z = f2bf(o.z); ob.w = f2bf(o.w);
    *(ushort4*)(xbf + base + c) = ob;
  }
}

extern "C" void kernel_launch(void* const* d_in, const int* in_sizes, int n_in,
                              void* d_out, int out_size, void* d_ws, size_t ws_size,
                              hipStream_t stream) {
  const float* x    = (const float*)d_in[0];
  const float* Wqkv = (const float*)d_in[1];
  const float* bqkv = (const float*)d_in[2];
  const float* Wout = (const float*)d_in[3];
  const float* bout = (const float*)d_in[4];
  const float* W1   = (const float*)d_in[5];
  const float* b1   = (const float*)d_in[6];
  const float* W2   = (const float*)d_in[7];
  const float* b2   = (const float*)d_in[8];
  const float* g1   = (const float*)d_in[9];
  const float* be1  = (const float*)d_in[10];
  const float* g2   = (const float*)d_in[11];
  const float* be2  = (const float*)d_in[12];

  static bool s_attr = false;
  if (!s_attr) {
    hipFuncSetAttribute((const void*)gemm256g,
                        hipFuncAttributeMaxDynamicSharedMemorySize, 131072);
    hipFuncSetAttribute((const void*)gemm256_qkv,
                        hipFuncAttributeMaxDynamicSharedMemorySize, 131072);
    s_attr = true;
  }

  char* w = (char*)d_ws;
  const size_t MB = 1048576;
  // r6-proven layout (max 160 MB):
  unsigned short* xb     = (unsigned short*)(w + 0 * MB);    //  8 MB  x bf16
  unsigned short* WqkvT  = (unsigned short*)(w + 8 * MB);    //  6 MB
  unsigned short* WoutT  = (unsigned short*)(w + 14 * MB);   //  2 MB
  unsigned short* W1T    = (unsigned short*)(w + 16 * MB);   //  8 MB
  unsigned short* W2T    = (unsigned short*)(w + 24 * MB);   //  8 MB
  unsigned short* Qb     = (unsigned short*)(w + 32 * MB);   //  8 MB  [b][h][t][d]
  unsigned short* Kb     = (unsigned short*)(w + 40 * MB);   //  8 MB  [b][h][t][d]
  unsigned short* Vtb    = (unsigned short*)(w + 48 * MB);   // 16 MB  [b][h][d][t]
  unsigned short* obuf   = (unsigned short*)(w + 64 * MB);   //  8 MB  attn o bf16
  float*          atno_p = (float*)(w + 72 * MB);            // 32 MB  Wout partials x2
  float*          x1     = (float*)(w + 104 * MB);           // 16 MB
  unsigned short* x1b    = (unsigned short*)(w + 120 * MB);  //  8 MB
  unsigned short* hb     = (unsigned short*)(w + 128 * MB);  // 32 MB  gelu(h) bf16
  float*          ffn_p  = (float*)(w + 32 * MB);            // 32 MB  W2 partials x2
  // (ffn_p reuses Qb/Kb/Vtb — all dead before the W2 GEMM)

  // fused prep: x cvt (4096 blocks) + 4 transposes (12288 tiles)
  prep_all<<<16384, 256, 0, stream>>>(x, Wqkv, Wout, W1, W2, xb, WqkvT, WoutT, W1T, W2T);

  // qkv = x @ Wqkv + bqkv -> bf16 Q (pre-scaled incl. log2e), K, V^T; 256^2 template
  gemm256_qkv<<<dim3(12, 16), 512, 131072, stream>>>(xb, WqkvT, bqkv, Qb, Kb, Vtb);
  // MFMA flash attention -> o (bf16); 1024 XCD-swizzled blocks, 4/CU, key-split waves
  attn_mfma<<<1024, 256, 0, stream>>>(Qb, Kb, Vtb, obuf);
  // attn_out partials = o @ Wout (128^2 split-K 2: 512 blocks = 2/CU; r6-proven)
  gemm_splitk<<<dim3(8, 32, 2), 256, 0, stream>>>(obuf, WoutT, atno_p, 4096, 1024, 1024, 512);
  // x1 = x + LN(p0 + p1 + bout)
  add_ln_red<2, 1><<<4096, 256, 0, stream>>>(x, atno_p, bout, g1, be1, x1, x1b);
  // h = gelu(x1 @ W1 + b1) -> bf16; 256^2 8-phase GEMM, 256 blocks = 1/CU
  gemm256g<<<dim3(16, 16), 512, 131072, stream>>>(x1b, W1T, b1, hb, 4096, 4096, 1024);
  // ffn partials = h @ W2 (128^2 split-K 2: 512 blocks = 2/CU, Ksl=2048; r6-proven)
  gemm_splitk<<<dim3(8, 32, 2), 256, 0, stream>>>(hb, W2T, ffn_p, 4096, 1024, 4096, 2048);
  // out = x1 + LN(p0+p1 + b2)
  add_ln_red<2, 0><<<4096, 256, 0, stream>>>(x1, ffn_p, b2, g2, be2, (float*)d_out, nullptr);
}

// Round 9
// 337.072 us; speedup vs baseline: 1.0761x; 1.0242x over previous
//
#include <hip/hip_runtime.h>
#include <cstdint>
#include <cstddef>

#define DIM 1024
#define HEADS 16
#define HD 64
#define DFF 4096
#define TSEQ 2048
#define EPS 1e-5f

// s_waitcnt immediates: vmcnt bits[3:0]|[15:14], expcnt bits[6:4], lgkmcnt bits[11:8]
#define WAITCNT_VM4 0xF74        // vmcnt=4, lgkm=15 (no wait)
#define WAITCNT_VM0 0xF70        // vmcnt=0, lgkm=15
#define WAITCNT_VM8 0xF78        // vmcnt=8, lgkm=15
#define WAITCNT_LGKM0 0xC07F     // lgkm=0, vmcnt=63 (no wait) -- drain DS, keep DMA in flight

typedef __bf16 bf16x8 __attribute__((ext_vector_type(8)));
typedef __bf16 bf16x4 __attribute__((ext_vector_type(4)));
typedef float floatx4 __attribute__((ext_vector_type(4)));

__device__ __forceinline__ unsigned short f2bf(float f) {
  union { float f; unsigned int u; } v; v.f = f;
  return (unsigned short)((v.u + 0x7FFFu + ((v.u >> 16) & 1u)) >> 16);
}

// raw v_exp_f32: computes 2^x (log2e is pre-folded into the Q scale)
__device__ __forceinline__ float exp2_fast(float x) {
#if __has_builtin(__builtin_amdgcn_exp2f)
  return __builtin_amdgcn_exp2f(x);
#else
  float r;
  asm("v_exp_f32 %0, %1" : "=v"(r) : "v"(x));
  return r;
#endif
}

// tanh-form GELU: max |err| vs exact-erf gelu ~3e-3 (negligible vs bf16 path noise)
__device__ __forceinline__ float gelu_f(float v) {
  const float u = v * (0.7978845608f + 0.0356774081f * v * v);
  const float e = __expf(2.0f * u);
  const float t = 1.0f - 2.0f / (e + 1.0f);
  return 0.5f * v * (1.0f + t);
}

__device__ __forceinline__ void async16(const void* g, void* l) {
  __builtin_amdgcn_global_load_lds(
      (const __attribute__((address_space(1))) void*)g,
      (__attribute__((address_space(3))) void*)l, 16, 0, 0);
}

// ---------------- fused prep: x->bf16 + 4 weight transposes (one launch) ----------------
__global__ __launch_bounds__(256) void prep_all(const float* __restrict__ x,
                                                const float* __restrict__ Wqkv,
                                                const float* __restrict__ Wout,
                                                const float* __restrict__ W1,
                                                const float* __restrict__ W2,
                                                unsigned short* __restrict__ xb,
                                                unsigned short* __restrict__ WqkvT,
                                                unsigned short* __restrict__ WoutT,
                                                unsigned short* __restrict__ W1T,
                                                unsigned short* __restrict__ W2T) {
  const int bid = blockIdx.x;
  const int tid = threadIdx.x;
  if (bid < 4096) {  // x -> bf16, float4 per thread
    const int i = bid * 256 + tid;
    float4 v = ((const float4*)x)[i];
    ushort4 o;
    o.x = f2bf(v.x); o.y = f2bf(v.y); o.z = f2bf(v.z); o.w = f2bf(v.w);
    ((ushort4*)xb)[i] = o;
    return;
  }
  int id = bid - 4096;
  const float* src; unsigned short* dst; int R, C, gx;
  if (id < 3072)      {            src = Wqkv; dst = WqkvT; R = 1024; C = 3072; gx = 96; }
  else if (id < 4096) { id -= 3072; src = Wout; dst = WoutT; R = 1024; C = 1024; gx = 32; }
  else if (id < 8192) { id -= 4096; src = W1;   dst = W1T;   R = 1024; C = 4096; gx = 128; }
  else                { id -= 8192; src = W2;   dst = W2T;   R = 4096; C = 1024; gx = 32; }
  const int c0 = (id % gx) * 32, r0 = (id / gx) * 32;
  const int tx = tid & 31, ty = tid >> 5;  // 32 x 8
  __shared__ float tile[32][33];
#pragma unroll
  for (int i = 0; i < 32; i += 8)
    tile[ty + i][tx] = src[(size_t)(r0 + ty + i) * C + c0 + tx];
  __syncthreads();
#pragma unroll
  for (int i = 0; i < 32; i += 8)
    dst[(size_t)(c0 + ty + i) * R + r0 + tx] = f2bf(tile[tx][ty + i]);
}

// ====== 3-stage K-loop (48 KB LDS, prefetch distance 2, 1 barrier/iter) ======
// Distance-2 prefetch fully covers HBM/L2 latency; used by the 128^2 kernels
// (qkv 768 blocks = 3/CU; splitk 512 blocks = 2/CU). r6-proven.
#define PIPELINED_KLOOP3(NIT)                                                        \
  auto issue = [&](int s, int k0) {                                                  \
    async16(Ab0 + k0, &lds[s][tid * 8]);                                             \
    async16(Ab1 + k0, &lds[s][2048 + tid * 8]);                                      \
    async16(Bb0 + k0, &lds[s][4096 + tid * 8]);                                      \
    async16(Bb1 + k0, &lds[s][6144 + tid * 8]);                                      \
  };                                                                                 \
  issue(0, 0);                                                                       \
  issue(1, 32);                                                                      \
  int sidx = 0;                                                                      \
  for (int k = 0; k < (NIT); k++) {                                                  \
    if (k < (NIT)-1) __builtin_amdgcn_s_waitcnt(WAITCNT_VM4);                        \
    else             __builtin_amdgcn_s_waitcnt(WAITCNT_VM0);                        \
    __builtin_amdgcn_s_barrier();                                                    \
    if (k + 2 < (NIT)) {                                                             \
      int s2 = sidx + 2; if (s2 >= 3) s2 -= 3;                                       \
      issue(s2, (k + 2) * 32);                                                       \
    }                                                                                \
    bf16x8 af[4], bg[4];                                                             \
    _Pragma("unroll")                                                                \
    for (int mi = 0; mi < 4; mi++)                                                   \
      af[mi] = *(const bf16x8*)&lds[sidx][(wm + mi * 16 + l16) * 32 + quad * 8];     \
    _Pragma("unroll")                                                                \
    for (int ni = 0; ni < 4; ni++)                                                   \
      bg[ni] = *(const bf16x8*)&lds[sidx][4096 + (wn + ni * 16 + l16) * 32 + quad * 8]; \
    _Pragma("unroll")                                                                \
    for (int mi = 0; mi < 4; mi++)                                                   \
      _Pragma("unroll")                                                              \
      for (int ni = 0; ni < 4; ni++)                                                 \
        acc[mi][ni] =                                                                \
            __builtin_amdgcn_mfma_f32_16x16x32_bf16(af[mi], bg[ni], acc[mi][ni], 0, 0, 0); \
    sidx = (sidx == 2) ? 0 : sidx + 1;                                               \
  }

// ======== 256x256-tile 4-phase GEMM (r6-proven), gelu+bf16 epilogue ========
// C[M,N] = gelu(A[M,K] @ Bt[N,K]^T + bias) as bf16. 512 threads = 8 waves (2M x 4N);
// per-wave output 128x64 (acc[8][4]); BK=64 per K-step, 64 MFMA/wave/K-step split into
// 4 phases x 16 MFMA. LDS 128 KiB: 2 K-step buffers x (A 256x64 | B 256x64), swizzled
// chunk^(row&7). ph0 issues ALL next-K-step staging; vmcnt(0) only at ph3.
// Grid 16x16 = 256 blocks = 1/CU. XCD remap (FIXED r9): each XCD owns a 4bx x 8by
// region -> its 4 B-panels (2 MB) stay L2-resident; previously the remap was dead
// (guarded on gridDim==32) and A-panels refetched into all 8 L2s.
__global__ __launch_bounds__(512, 2) void gemm256g(const unsigned short* __restrict__ A,
                                                   const unsigned short* __restrict__ Bt,
                                                   const float* __restrict__ bias,
                                                   unsigned short* __restrict__ Cout,
                                                   int M, int N, int K) {
  extern __shared__ char smem[];  // 131072
  const int tid = threadIdx.x;
  int bxx = blockIdx.x, byy = blockIdx.y;
  {  // XCD 2D tiling for the 16x16 grid (bijective; hardware assigns id%8 -> XCD)
    const int id = byy * 16 + bxx;          // hardware linear order (x fastest)
    const int xcd = id & 7, sub = id >> 3;  // sub 0..31 within this XCD
    bxx = (xcd & 3) * 4 + (sub & 3);
    byy = (xcd >> 2) * 8 + (sub >> 2);
  }
  const int bm = byy * 256, bn = bxx * 256;
  const int lane = tid & 63, wv = tid >> 6;
  const int l16 = lane & 15, quad = lane >> 4;
  const int wr = wv >> 2, wc = wv & 3;  // 2M x 4N wave grid

  // staging source (pre-swizzled): thread t covers half-row (t>>3)+64j, chunk (t&7)^((t>>3)&7)
  const int srow = tid >> 3;                    // 0..63
  const int scc = (tid & 7) ^ (srow & 7);
  const unsigned short* Asrc = A + (size_t)(bm + srow) * K + scc * 8;
  const unsigned short* Bsrc = Bt + (size_t)(bn + srow) * K + scc * 8;

  auto stageKstep = [&](int buf, int kk) {
    char* dA = smem + buf * 65536;
    char* dB = dA + 32768;
#pragma unroll
    for (int h = 0; h < 2; h++)
#pragma unroll
      for (int j = 0; j < 2; j++) {
        async16(Asrc + (size_t)(h * 128 + 64 * j) * K + kk,
                dA + h * 16384 + (j * 512 + tid) * 16);
        async16(Bsrc + (size_t)(h * 128 + 64 * j) * K + kk,
                dB + h * 16384 + (j * 512 + tid) * 16);
      }
  };

  floatx4 acc[8][4] = {};

  // prologue: stage K-step 0 into buf 0, full drain
  stageKstep(0, 0);
  __builtin_amdgcn_s_waitcnt(WAITCNT_VM0);
  __builtin_amdgcn_s_barrier();

  const int NG = K >> 6;  // K-steps of 64
  for (int g = 0; g < NG; g++) {
    const int p = g & 1;
    const char* Ab = smem + p * 65536 + wr * 16384;                  // this wave's A half
    const char* Bb = smem + p * 65536 + 32768 + (wc >> 1) * 16384;   // this wave's B half
    bf16x8 bg[4][2];
#pragma unroll
    for (int q = 0; q < 4; q++) {
      if (q == 0) {
        if (g + 1 < NG) stageKstep(p ^ 1, (g + 1) << 6);
#pragma unroll
        for (int ni = 0; ni < 4; ni++) {
          const int lr = (wc & 1) * 64 + ni * 16 + l16;
#pragma unroll
          for (int ks = 0; ks < 2; ks++)
            bg[ni][ks] = *(const bf16x8*)(Bb + lr * 128 +
                                          (((quad + 4 * ks) ^ (lr & 7)) * 16));
        }
      }
      bf16x8 af[2][2];
#pragma unroll
      for (int m = 0; m < 2; m++) {
        const int lr = (q * 2 + m) * 16 + l16;
#pragma unroll
        for (int ks = 0; ks < 2; ks++)
          af[m][ks] = *(const bf16x8*)(Ab + lr * 128 +
                                       (((quad + 4 * ks) ^ (lr & 7)) * 16));
      }
      __builtin_amdgcn_s_barrier();
      __builtin_amdgcn_s_waitcnt(WAITCNT_LGKM0);
      __builtin_amdgcn_s_setprio(1);
#pragma unroll
      for (int ks = 0; ks < 2; ks++)
#pragma unroll
        for (int ni = 0; ni < 4; ni++)
#pragma unroll
          for (int m = 0; m < 2; m++)
            acc[q * 2 + m][ni] = __builtin_amdgcn_mfma_f32_16x16x32_bf16(
                af[m][ks], bg[ni][ks], acc[q * 2 + m][ni], 0, 0, 0);
      __builtin_amdgcn_s_setprio(0);
      if (q == 3) __builtin_amdgcn_s_waitcnt(WAITCNT_VM0);  // next-K-step DMA landed
      __builtin_amdgcn_s_barrier();
    }
  }

  // epilogue: gelu + bias -> bf16, coalesced via per-wave 16x64 LDS transpose tile
  __syncthreads();
  unsigned short* eb = (unsigned short*)smem + wv * 1152;  // 16 rows x 72 shorts
  float bvv[4];
#pragma unroll
  for (int ni = 0; ni < 4; ni++) bvv[ni] = bias[bn + wc * 64 + ni * 16 + l16];
  const int lrow = lane >> 2, ck = lane & 3;
#pragma unroll
  for (int mi = 0; mi < 8; mi++) {
#pragma unroll
    for (int ni = 0; ni < 4; ni++)
#pragma unroll
      for (int r = 0; r < 4; r++)
        eb[(quad * 4 + r) * 72 + ni * 16 + l16] =
            f2bf(gelu_f(acc[mi][ni][r] + bvv[ni]));
    __syncthreads();
    unsigned short* gp =
        Cout + (size_t)(bm + wr * 128 + mi * 16 + lrow) * N + bn + wc * 64;
#pragma unroll
    for (int j = 0; j < 2; j++)
      *(uint4*)(gp + j * 32 + ck * 8) = *(const uint4*)&eb[lrow * 72 + j * 32 + ck * 8];
    __syncthreads();
  }
}

// ------- split-K GEMM: Cp[z][M,N] = A[:, z*Ksl:(z+1)*Ksl] @ Bt[:, same]^T (fp32) -------
// 128^2 tile, 3-stage loop; 2D XCD tiling over (bx, by, z). r6-proven (<=60 us both uses).
__global__ __launch_bounds__(256) void gemm_splitk(const unsigned short* __restrict__ A,
                                                   const unsigned short* __restrict__ Bt,
                                                   float* __restrict__ Cp,
                                                   int M, int N, int Ktot, int Ksl) {
  __shared__ unsigned short lds[3][8192];
  const int tid = threadIdx.x;
  const int id = (blockIdx.z * 32 + blockIdx.y) * 8 + blockIdx.x;  // linear (x fastest)
  const int xcd = id & 7, sub = id >> 3;
  const int bxx = sub & 7;
  const int byz = xcd * (gridDim.z * 4) + (sub >> 3);  // 32*z/8 = 4z per XCD
  const int byy = byz & 31, bz = byz >> 5;
  const int bm = byy * 128, bn = bxx * 128;
  const int koff = bz * Ksl;
  const int wave = tid >> 6, lane = tid & 63;
  const int l16 = lane & 15, quad = lane >> 4;
  const int wm = (wave >> 1) * 64, wn = (wave & 1) * 64;

  floatx4 acc[4][4] = {};

  const int srow = tid >> 2;
  const int scol = (tid & 3) * 8;

  const unsigned short* Ab0 = A + (size_t)(bm + srow) * Ktot + koff + scol;
  const unsigned short* Ab1 = A + (size_t)(bm + 64 + srow) * Ktot + koff + scol;
  const unsigned short* Bb0 = Bt + (size_t)(bn + srow) * Ktot + koff + scol;
  const unsigned short* Bb1 = Bt + (size_t)(bn + 64 + srow) * Ktot + koff + scol;

  const int nit = Ksl >> 5;
  PIPELINED_KLOOP3(nit)

  float* out = Cp + (size_t)bz * M * (size_t)N;
#pragma unroll
  for (int ni = 0; ni < 4; ni++) {
    const int col = bn + wn + ni * 16 + l16;
#pragma unroll
    for (int mi = 0; mi < 4; mi++) {
      const int row0 = bm + wm + mi * 16 + quad * 4;
#pragma unroll
      for (int r = 0; r < 4; r++)
        out[(size_t)(row0 + r) * N + col] = acc[mi][ni][r];
    }
  }
}

// ------- QKV GEMM: C[4096,3072] = xb @ WqkvT^T + bqkv, split-written as bf16 -------
// Q is pre-scaled by 1/sqrt(hd) * log2(e) so attention can use raw v_exp_f32 (2^x).
// 128^2 tile, 3-stage loop (r6-proven best for this kernel); 2D XCD tiling
// (grid 24x32): per XCD a 6bx x 16by sub-tile.
__global__ __launch_bounds__(256) void gemm_qkv(const unsigned short* __restrict__ A,
                                                const unsigned short* __restrict__ Bt,
                                                const float* __restrict__ bias,
                                                unsigned short* __restrict__ Qg,
                                                unsigned short* __restrict__ Kg,
                                                unsigned short* __restrict__ Vtg) {
  const int K = 1024;
  __shared__ unsigned short lds[3][8192];
  const int tid = threadIdx.x;
  const int id = blockIdx.y * 24 + blockIdx.x;  // linear (x fastest)
  const int xcd = id & 7, sub = id >> 3;        // sub 0..95
  const int bxx = (xcd & 3) * 6 + sub % 6;
  const int byy = (xcd >> 2) * 16 + sub / 6;
  const int bm = byy * 128, bn = bxx * 128;
  const int wave = tid >> 6, lane = tid & 63;
  const int l16 = lane & 15, quad = lane >> 4;
  const int wm = (wave >> 1) * 64, wn = (wave & 1) * 64;

  floatx4 acc[4][4] = {};

  const int srow = tid >> 2;
  const int scol = (tid & 3) * 8;

  const unsigned short* Ab0 = A + (size_t)(bm + srow) * K + scol;
  const unsigned short* Ab1 = A + (size_t)(bm + 64 + srow) * K + scol;
  const unsigned short* Bb0 = Bt + (size_t)(bn + srow) * K + scol;
  const unsigned short* Bb1 = Bt + (size_t)(bn + 64 + srow) * K + scol;

  const int nit = K >> 5;
  PIPELINED_KLOOP3(nit)

  const float QSCALE = 0.125f * 1.44269504089f;  // 1/sqrt(64) * log2(e)
#pragma unroll
  for (int ni = 0; ni < 4; ni++) {
    const int col = bn + wn + ni * 16 + l16;   // 0..3071
    const float bv = bias[col];
    const int sec = col >> 10;                 // 0=q 1=k 2=v
    const int cc = col & 1023;
    const int hh = cc >> 6, dd = cc & 63;
#pragma unroll
    for (int mi = 0; mi < 4; mi++) {
      const int row0 = bm + wm + mi * 16 + quad * 4;   // token row (0..4095)
      const int b2 = row0 >> 11, tt0 = row0 & 2047;
      if (sec == 0) {
        unsigned short* q = Qg + ((size_t)(b2 * HEADS + hh) * TSEQ + tt0) * HD + dd;
#pragma unroll
        for (int r = 0; r < 4; r++)
          q[(size_t)r * HD] = f2bf((acc[mi][ni][r] + bv) * QSCALE);
      } else if (sec == 1) {
        unsigned short* k = Kg + ((size_t)(b2 * HEADS + hh) * TSEQ + tt0) * HD + dd;
#pragma unroll
        for (int r = 0; r < 4; r++)
          k[(size_t)r * HD] = f2bf(acc[mi][ni][r] + bv);
      } else {
        ushort4 o;
        o.x = f2bf(acc[mi][ni][0] + bv);
        o.y = f2bf(acc[mi][ni][1] + bv);
        o.z = f2bf(acc[mi][ni][2] + bv);
        o.w = f2bf(acc[mi][ni][3] + bv);
        *(ushort4*)(Vtg + ((size_t)(b2 * HEADS + hh) * HD + dd) * TSEQ + tt0) = o;
      }
    }
  }
}

// ---------------- MFMA flash attention (r6-proven, unchanged) ----------------
// grid 1024 (XCD-swizzled), block 256 = 4 waves. Wave w = (qg = w>>1, kh = w&1):
// 32 queries x 32-key half. P tile: per-wave 16x32 bf16 at 72 B row stride
// (conflict-free; measured SQ_LDS_BANK_CONFLICT 5.5M -> 262K). 2-stage K/V pipeline,
// counted vmcnt(4), lgkm-only drain at the reuse barrier, prefetch distance 2.
__global__ __launch_bounds__(256, 4) void attn_mfma(const unsigned short* __restrict__ Qg,
                                                    const unsigned short* __restrict__ Kg,
                                                    const unsigned short* __restrict__ Vtg,
                                                    unsigned short* __restrict__ ob) {
  __shared__ __align__(16) char smem[40960];
  unsigned short* QPs = (unsigned short*)smem;  // 8KB: Q stage, then 4x 1152B P tiles

  // XCD-aware swizzle: each XCD gets 128 consecutive logical tiles = 4 (b,h) groups.
  const int bid = blockIdx.x;
  const int lid = (bid & 7) * 128 + (bid >> 3);
  const int qt = lid & 31;          // 32 query-tiles of 64 per (b,h)
  const int h = (lid >> 5) & 15;
  const int b = lid >> 9;
  const int tid = threadIdx.x;
  const int w = tid >> 6, lane = tid & 63, l16 = lane & 15, quad = lane >> 4;
  const int qg = w >> 1;   // query group: rows qg*32 .. qg*32+31
  const int kh = w & 1;    // key half: keys kh*32 .. kh*32+31 of each chunk

  const int r0 = tid >> 3;                 // 0..31
  const int c0 = (tid & 7) ^ (r0 & 7);     // swizzled 16B chunk

  const char* Qbase = (const char*)(Qg + ((size_t)(b * HEADS + h) * TSEQ + qt * 64) * HD);
  const char* Kbase = (const char*)(Kg + (size_t)(b * HEADS + h) * TSEQ * HD);
  const char* Vbase = (const char*)(Vtg + (size_t)(b * HEADS + h) * HD * TSEQ);

  auto Ksp = [&](int s) -> char* { return smem + 8192 + s * 8192; };
  auto Vsp = [&](int s) -> char* { return smem + 24576 + s * 8192; };

  auto issueKV = [&](int s, int ch) {
    const size_t koff = (size_t)ch * 64;
#pragma unroll
    for (int i = 0; i < 2; i++) {
      async16(Kbase + (koff + r0 + i * 32) * 128 + c0 * 16, Ksp(s) + (i * 256 + tid) * 16);
      async16(Vbase + (size_t)(r0 + i * 32) * (TSEQ * 2) + koff * 2 + c0 * 16,
              Vsp(s) + (i * 256 + tid) * 16);
    }
  };

  // stage Q (2 loads/thread) then K/V chunks 0,1 (4 loads/thread each)
#pragma unroll
  for (int i = 0; i < 2; i++)
    async16(Qbase + (size_t)(r0 + i * 32) * 128 + c0 * 16, (char*)QPs + (i * 256 + tid) * 16);
  issueKV(0, 0);
  issueKV(1, 1);

  __builtin_amdgcn_s_waitcnt(WAITCNT_VM8);  // Q (oldest 2) done; 8 KV stay in flight
  __builtin_amdgcn_s_barrier();

  // preload Q a-fragments (rows of this wave's query group)
  bf16x8 qf[2][2];
#pragma unroll
  for (int mi = 0; mi < 2; mi++)
#pragma unroll
    for (int kt = 0; kt < 2; kt++) {
      const int row = qg * 32 + mi * 16 + l16;
      qf[mi][kt] = *(const bf16x8*)((const char*)QPs + row * 128 +
                                    (((quad + 4 * kt) ^ (row & 7)) * 16));
    }
  // Q reads must land before ANY wave's P writes overlay this region (cross-wave WAR)
  __builtin_amdgcn_s_waitcnt(WAITCNT_LGKM0);
  __builtin_amdgcn_sched_barrier(0);

  union { unsigned short u[8]; bf16x8 b; } onesu;
#pragma unroll
  for (int j = 0; j < 8; j++) onesu.u[j] = 0x3F80;  // bf16 1.0
  const bf16x8 ones = onesu.b;

  floatx4 oacc[2][5] = {};            // [mi][nj]; nj==4 accumulates the row sum l
  char* Pw = (char*)QPs + w * 1152;   // wave-private 16x32 bf16 P tile, 72B rows

  const int NC = TSEQ / 64;
  int sidx = 0;
  for (int ch = 0; ch < NC; ch++) {
    if (ch < NC - 1) __builtin_amdgcn_s_waitcnt(WAITCNT_VM4);
    else             __builtin_amdgcn_s_waitcnt(WAITCNT_VM0);
    __builtin_amdgcn_s_barrier();   // all waves' DMA for chunk ch landed

    // S = Q K_half^T (scale+log2e folded into Q)
    floatx4 sacc[2][2] = {};
    __builtin_amdgcn_s_setprio(1);
#pragma unroll
    for (int kt = 0; kt < 2; kt++) {
#pragma unroll
      for (int ni = 0; ni < 2; ni++) {
        const int krow = kh * 32 + ni * 16 + l16;
        bf16x8 kf = *(const bf16x8*)(Ksp(sidx) + krow * 128 +
                                     (((quad + 4 * kt) ^ (krow & 7)) * 16));
#pragma unroll
        for (int mi = 0; mi < 2; mi++)
          sacc[mi][ni] =
              __builtin_amdgcn_mfma_f32_16x16x32_bf16(qf[mi][kt], kf, sacc[mi][ni], 0, 0, 0);
      }
    }
    __builtin_amdgcn_s_setprio(0);

    // P = 2^S; per-mi: write 16-row tile (truncating bf16, conflict-free 72B stride),
    // then read this mi's A-fragments back. Buffer reused across mi.
    bf16x8 pf[2];
#pragma unroll
    for (int mi = 0; mi < 2; mi++) {
#pragma unroll
      for (int ni = 0; ni < 2; ni++)
#pragma unroll
        for (int r = 0; r < 4; r++) {
          const float p = exp2_fast(sacc[mi][ni][r]);
          const unsigned int pu = __builtin_bit_cast(unsigned int, p);
          *((unsigned short*)(Pw + (quad * 4 + r) * 72 + (ni * 16 + l16) * 2)) =
              (unsigned short)(pu >> 16);
        }
      union { bf16x8 v8; bf16x4 v4[2]; } u;
      u.v4[0] = *(const bf16x4*)(Pw + l16 * 72 + quad * 16);
      u.v4[1] = *(const bf16x4*)(Pw + l16 * 72 + quad * 16 + 8);
      pf[mi] = u.v8;
    }

    // O += P V_half ; l += P 1   (k = 32 keys: single MFMA k-depth)
    __builtin_amdgcn_s_setprio(1);
#pragma unroll
    for (int nj = 0; nj < 4; nj++) {
      const int vrow = nj * 16 + l16;
      bf16x8 vf = *(const bf16x8*)(Vsp(sidx) + vrow * 128 +
                                   (((quad + 4 * kh) ^ (vrow & 7)) * 16));
#pragma unroll
      for (int mi = 0; mi < 2; mi++)
        oacc[mi][nj] = __builtin_amdgcn_mfma_f32_16x16x32_bf16(pf[mi], vf, oacc[mi][nj], 0, 0, 0);
    }
#pragma unroll
    for (int mi = 0; mi < 2; mi++)
      oacc[mi][4] = __builtin_amdgcn_mfma_f32_16x16x32_bf16(pf[mi], ones, oacc[mi][4], 0, 0, 0);
    __builtin_amdgcn_s_setprio(0);

    // drain this wave's DS reads (keep DMA in flight), then allow stage reuse
    __builtin_amdgcn_s_waitcnt(WAITCNT_LGKM0);
    __builtin_amdgcn_s_barrier();
    if (ch + 2 < NC) issueKV(sidx, ch + 2);
    sidx ^= 1;
  }

  // ---- key-half combine: kh=1 waves stage partials, kh=0 waves reduce+store ----
  __syncthreads();  // all stages dead; smem reusable
  float* Op = (float*)smem + qg * (32 * 66);  // 32 rows x 66 floats (64 O + 1 l + pad)
  if (kh == 1) {
#pragma unroll
    for (int mi = 0; mi < 2; mi++)
#pragma unroll
      for (int r = 0; r < 4; r++) {
        const int row = mi * 16 + quad * 4 + r;
#pragma unroll
        for (int nj = 0; nj < 4; nj++)
          Op[row * 66 + nj * 16 + l16] = oacc[mi][nj][r];
        if (l16 == 0) Op[row * 66 + 64] = oacc[mi][4][r];
      }
  }
  __syncthreads();
  if (kh == 0) {
#pragma unroll
    for (int mi = 0; mi < 2; mi++)
#pragma unroll
      for (int r = 0; r < 4; r++) {
        const int row = mi * 16 + quad * 4 + r;
        const float inv = 1.0f / (oacc[mi][4][r] + Op[row * 66 + 64]);
        const int t = qt * 64 + qg * 32 + row;
        unsigned short* orow = ob + (size_t)(b * TSEQ + t) * DIM + h * HD + l16;
#pragma unroll
        for (int nj = 0; nj < 4; nj++)
          orow[nj * 16] = f2bf((oacc[mi][nj][r] + Op[row * 66 + nj * 16 + l16]) * inv);
      }
  }
}

// ------- x_out = x_in + LN( sum_p parts[p] + bias ; g, b ); optional bf16 copy -------
template <int NP, int WBF>
__global__ __launch_bounds__(256) void add_ln_red(const float* __restrict__ xin,
                                                  const float* __restrict__ parts,
                                                  const float* __restrict__ bias,
                                                  const float* __restrict__ gw,
                                                  const float* __restrict__ bw,
                                                  float* __restrict__ xout,
                                                  unsigned short* __restrict__ xbf) {
  const size_t MN = (size_t)4096 * DIM;
  const int row = blockIdx.x;
  const int tid = threadIdx.x;
  const int c = tid * 4;
  const size_t base = (size_t)row * DIM;
  float4 v = *(const float4*)(parts + base + c);
#pragma unroll
  for (int p = 1; p < NP; p++) {
    float4 t = *(const float4*)(parts + p * MN + base + c);
    v.x += t.x; v.y += t.y; v.z += t.z; v.w += t.w;
  }
  float4 bb = *(const float4*)(bias + c);
  v.x += bb.x; v.y += bb.y; v.z += bb.z; v.w += bb.w;

  float s = v.x + v.y + v.z + v.w;
  float s2 = v.x * v.x + v.y * v.y + v.z * v.z + v.w * v.w;
#pragma unroll
  for (int off = 1; off < 64; off <<= 1) {
    s += __shfl_xor(s, off);
    s2 += __shfl_xor(s2, off);
  }
  __shared__ float rsum[4], rsq[4];
  if ((tid & 63) == 0) { rsum[tid >> 6] = s; rsq[tid >> 6] = s2; }
  __syncthreads();
  s = rsum[0] + rsum[1] + rsum[2] + rsum[3];
  s2 = rsq[0] + rsq[1] + rsq[2] + rsq[3];
  const float mu = s * (1.0f / DIM);
  const float var = s2 * (1.0f / DIM) - mu * mu;
  const float rstd = rsqrtf(var + EPS);
  float4 xv = *(const float4*)(xin + base + c);
  float4 gv = *(const float4*)(gw + c);
  float4 bv = *(const float4*)(bw + c);
  float4 o;
  o.x = xv.x + (v.x - mu) * rstd * gv.x + bv.x;
  o.y = xv.y + (v.y - mu) * rstd * gv.y + bv.y;
  o.z = xv.z + (v.z - mu) * rstd * gv.z + bv.z;
  o.w = xv.w + (v.w - mu) * rstd * gv.w + bv.w;
  *(float4*)(xout + base + c) = o;
  if (WBF) {
    ushort4 ob;
    ob.x = f2bf(o.x); ob.y = f2bf(o.y); ob.z = f2bf(o.z); ob.w = f2bf(o.w);
    *(ushort4*)(xbf + base + c) = ob;
  }
}

extern "C" void kernel_launch(void* const* d_in, const int* in_sizes, int n_in,
                              void* d_out, int out_size, void* d_ws, size_t ws_size,
                              hipStream_t stream) {
  const float* x    = (const float*)d_in[0];
  const float* Wqkv = (const float*)d_in[1];
  const float* bqkv = (const float*)d_in[2];
  const float* Wout = (const float*)d_in[3];
  const float* bout = (const float*)d_in[4];
  const float* W1   = (const float*)d_in[5];
  const float* b1   = (const float*)d_in[6];
  const float* W2   = (const float*)d_in[7];
  const float* b2   = (const float*)d_in[8];
  const float* g1   = (const float*)d_in[9];
  const float* be1  = (const float*)d_in[10];
  const float* g2   = (const float*)d_in[11];
  const float* be2  = (const float*)d_in[12];

  static bool s_attr = false;
  if (!s_attr) {
    hipFuncSetAttribute((const void*)gemm256g,
                        hipFuncAttributeMaxDynamicSharedMemorySize, 131072);
    s_attr = true;
  }

  char* w = (char*)d_ws;
  const size_t MB = 1048576;
  // r6-proven layout (max 160 MB):
  unsigned short* xb     = (unsigned short*)(w + 0 * MB);    //  8 MB  x bf16
  unsigned short* WqkvT  = (unsigned short*)(w + 8 * MB);    //  6 MB
  unsigned short* WoutT  = (unsigned short*)(w + 14 * MB);   //  2 MB
  unsigned short* W1T    = (unsigned short*)(w + 16 * MB);   //  8 MB
  unsigned short* W2T    = (unsigned short*)(w + 24 * MB);   //  8 MB
  unsigned short* Qb     = (unsigned short*)(w + 32 * MB);   //  8 MB  [b][h][t][d]
  unsigned short* Kb     = (unsigned short*)(w + 40 * MB);   //  8 MB  [b][h][t][d]
  unsigned short* Vtb    = (unsigned short*)(w + 48 * MB);   // 16 MB  [b][h][d][t]
  unsigned short* obuf   = (unsigned short*)(w + 64 * MB);   //  8 MB  attn o bf16
  float*          atno_p = (float*)(w + 72 * MB);            // 32 MB  Wout partials x2
  float*          x1     = (float*)(w + 104 * MB);           // 16 MB
  unsigned short* x1b    = (unsigned short*)(w + 120 * MB);  //  8 MB
  unsigned short* hb     = (unsigned short*)(w + 128 * MB);  // 32 MB  gelu(h) bf16
  float*          ffn_p  = (float*)(w + 32 * MB);            // 32 MB  W2 partials x2
  // (ffn_p reuses Qb/Kb/Vtb — all dead before the W2 GEMM)

  // fused prep: x cvt (4096 blocks) + 4 transposes (12288 tiles)
  prep_all<<<16384, 256, 0, stream>>>(x, Wqkv, Wout, W1, W2, xb, WqkvT, WoutT, W1T, W2T);

  // qkv = x @ Wqkv + bqkv -> bf16 Q (pre-scaled incl. log2e), K, V^T; 128^2 KLOOP3
  gemm_qkv<<<dim3(24, 32), 256, 0, stream>>>(xb, WqkvT, bqkv, Qb, Kb, Vtb);
  // MFMA flash attention -> o (bf16); 1024 XCD-swizzled blocks, 4/CU, key-split waves
  attn_mfma<<<1024, 256, 0, stream>>>(Qb, Kb, Vtb, obuf);
  // attn_out partials = o @ Wout (128^2 split-K 2: 512 blocks = 2/CU; r6-proven)
  gemm_splitk<<<dim3(8, 32, 2), 256, 0, stream>>>(obuf, WoutT, atno_p, 4096, 1024, 1024, 512);
  // x1 = x + LN(p0 + p1 + bout)
  add_ln_red<2, 1><<<4096, 256, 0, stream>>>(x, atno_p, bout, g1, be1, x1, x1b);
  // h = gelu(x1 @ W1 + b1) -> bf16; 256^2 GEMM, 256 blocks = 1/CU, XCD remap FIXED
  gemm256g<<<dim3(16, 16), 512, 131072, stream>>>(x1b, W1T, b1, hb, 4096, 4096, 1024);
  // ffn partials = h @ W2 (128^2 split-K 2: 512 blocks = 2/CU, Ksl=2048; r6-proven)
  gemm_splitk<<<dim3(8, 32, 2), 256, 0, stream>>>(hb, W2T, ffn_p, 4096, 1024, 4096, 2048);
  // out = x1 + LN(p0+p1 + b2)
  add_ln_red<2, 0><<<4096, 256, 0, stream>>>(x1, ffn_p, b2, g2, be2, (float*)d_out, nullptr);
}